// Round 1
// baseline (6601.299 us; speedup 1.0000x reference)
//
#include <hip/hip_runtime.h>
#include <hip/hip_bf16.h>
#include <math.h>

#define BB 32
#define TT 128
#define TD 127
#define EMB 256
#define HID 512
#define G4 2048
#define NV 10000

// ---------------- GEMM: X[m,:] = embed[tok(m)] @ W + bias ----------------
// M x 2048, K=256.  tok(m): t=m>>5, b=m&31, ids[b*128+t]
__global__ __launch_bounds__(256) void gemm_x(const int* __restrict__ ids,
        const float* __restrict__ embed, const float* __restrict__ W,
        const float* __restrict__ bias, float* __restrict__ X, int M)
{
    __shared__ float As[16][128];
    __shared__ float Bs[16][128];
    __shared__ int toks[128];
    const int tid = threadIdx.x;
    const int m0 = blockIdx.y * 128, n0 = blockIdx.x * 128;
    if (tid < 128) {
        int mr = m0 + tid, tk = 0;
        if (mr < M) { int t = mr >> 5, b = mr & 31; tk = ids[b*TT + t]; }
        toks[tid] = tk;
    }
    __syncthreads();
    float acc[8][8] = {};
    const int ty = tid >> 4, tx = tid & 15;
    for (int kt = 0; kt < EMB; kt += 16) {
        #pragma unroll
        for (int i = 0; i < 2; i++) {
            int idx = tid*2 + i;
            int row = idx >> 2, k4 = (idx & 3)*4;
            float4 a = *(const float4*)&embed[(size_t)toks[row]*EMB + kt + k4];
            As[k4+0][row] = a.x; As[k4+1][row] = a.y; As[k4+2][row] = a.z; As[k4+3][row] = a.w;
        }
        #pragma unroll
        for (int i = 0; i < 2; i++) {
            int idx = tid*2 + i;
            int kr = idx >> 5, c4 = (idx & 31)*4;
            *(float4*)&Bs[kr][c4] = *(const float4*)&W[(size_t)(kt+kr)*G4 + n0 + c4];
        }
        __syncthreads();
        #pragma unroll
        for (int k = 0; k < 16; k++) {
            float a8[8], b8[8];
            #pragma unroll
            for (int i = 0; i < 8; i++) a8[i] = As[k][ty*8+i];
            #pragma unroll
            for (int j = 0; j < 8; j++) b8[j] = Bs[k][tx*8+j];
            #pragma unroll
            for (int i = 0; i < 8; i++) {
                #pragma unroll
                for (int j = 0; j < 8; j++)
                    acc[i][j] = fmaf(a8[i], b8[j], acc[i][j]);
            }
        }
        __syncthreads();
    }
    #pragma unroll
    for (int i = 0; i < 8; i++) {
        int mr = m0 + ty*8 + i;
        if (mr < M) {
            #pragma unroll
            for (int j = 0; j < 8; j += 4) {
                int nc = n0 + tx*8 + j;
                float4 v;
                v.x = acc[i][j+0] + bias[nc+0];
                v.y = acc[i][j+1] + bias[nc+1];
                v.z = acc[i][j+2] + bias[nc+2];
                v.w = acc[i][j+3] + bias[nc+3];
                *(float4*)&X[(size_t)mr*G4 + nc] = v;
            }
        }
    }
}

// ---------------- One LSTM time step ----------------
// grid 256 blocks x 256 thr. block: bq=blk&7 -> 4 batch rows; ublk=blk>>3 -> 16 units.
// thread: b_loc=tid>>6, gate=(tid>>4)&3, u=tid&15.
__global__ __launch_bounds__(256) void lstm_step(const float* __restrict__ X_t,
        const float* __restrict__ Whh, const float* __restrict__ h_in,
        float* __restrict__ h_out, float* __restrict__ c, float* __restrict__ hs_out)
{
    const int tid = threadIdx.x;
    const int ublk = blockIdx.x >> 3, bq = blockIdx.x & 7;
    const int b_loc = tid >> 6, lane = tid & 63, gate = lane >> 4, u = lane & 15;
    const int b = bq*4 + b_loc;
    const int unit = ublk*16 + u;
    const int col = gate*512 + unit;
    const float* hrow = h_in + b*HID;
    const float* wcol = Whh + col;
    float a0=0.f, a1=0.f, a2=0.f, a3=0.f;
    #pragma unroll 4
    for (int k = 0; k < HID; k += 4) {
        a0 = fmaf(hrow[k+0], wcol[(k+0)*G4], a0);
        a1 = fmaf(hrow[k+1], wcol[(k+1)*G4], a1);
        a2 = fmaf(hrow[k+2], wcol[(k+2)*G4], a2);
        a3 = fmaf(hrow[k+3], wcol[(k+3)*G4], a3);
    }
    float acc = X_t[b*G4 + col] + ((a0+a1)+(a2+a3));
    float act = (gate == 2) ? tanhf(acc) : (1.f/(1.f + expf(-acc)));
    __shared__ float gl[4][4][16];
    gl[b_loc][gate][u] = act;
    __syncthreads();
    if (gate == 0) {
        float i_s = gl[b_loc][0][u], f_s = gl[b_loc][1][u];
        float g_t = gl[b_loc][2][u], o_s = gl[b_loc][3][u];
        int idx = b*HID + unit;
        float cn = f_s * c[idx] + i_s * g_t;
        c[idx] = cn;
        float hn = o_s * tanhf(cn);
        h_out[idx] = hn;
        if (hs_out) hs_out[idx] = hn;
    }
}

// ---------------- transpose fc_W (512 x 10000) -> (10000 x 512) ----------------
__global__ void transpose_fc(const float* __restrict__ W, float* __restrict__ Wt)
{
    __shared__ float tile[32][33];
    int v0 = blockIdx.x*32, k0 = blockIdx.y*32;
    int tx = threadIdx.x, ty = threadIdx.y;  // (32,8)
    #pragma unroll
    for (int r = 0; r < 32; r += 8) {
        int k = k0 + ty + r, v = v0 + tx;
        tile[ty+r][tx] = (v < NV) ? W[(size_t)k*NV + v] : 0.f;
    }
    __syncthreads();
    #pragma unroll
    for (int r = 0; r < 32; r += 8) {
        int v = v0 + ty + r, k = k0 + tx;
        if (v < NV) Wt[(size_t)v*HID + k] = tile[tx][ty+r];
    }
}

// ---------------- norms for rigorous logit bound ----------------
__global__ void wnorm(const float* __restrict__ W, const float* __restrict__ bvec,
                      unsigned int* __restrict__ scal)
{
    int v = blockIdx.x*256 + threadIdx.x;
    if (v < NV) {
        float s = 0.f;
        for (int k = 0; k < HID; k++) { float w = W[(size_t)k*NV + v]; s = fmaf(w, w, s); }
        atomicMax(&scal[0], __float_as_uint(s));
        atomicMax(&scal[1], __float_as_uint(fabsf(bvec[v])));
    }
}

__global__ void hnorm(const float* __restrict__ hs, unsigned int* __restrict__ scal)
{
    int r = blockIdx.x, lane = threadIdx.x;  // 64 threads
    float s = 0.f;
    for (int k = lane; k < HID; k += 64) { float x = hs[(size_t)r*HID + k]; s = fmaf(x, x, s); }
    for (int o = 32; o; o >>= 1) s += __shfl_down(s, o);
    if (lane == 0) atomicMax(&scal[2], __float_as_uint(s));
}

// ---------------- routing: exclusive cumsum of mask; winners for unmasked ----------------
__global__ void routing(const int* __restrict__ ids, const int* __restrict__ mask,
                        int* __restrict__ exclk, int* __restrict__ winner)
{
    int b = blockIdx.x;          // 32 blocks, 128 threads
    __shared__ int pre[TT];
    int t = threadIdx.x;
    if (t == 0) { int s = 0; for (int i = 0; i < TT; i++) { pre[i] = s; s += mask[b*TT+i]; } }
    __syncthreads();
    exclk[b*TT + t] = pre[t];
    if (mask[b*TT + t] == 0) winner[b*TT + t] = ids[b*TT + t];
}

// ---------------- per-row gumbel max (masked rows, t>=1) ----------------
__global__ __launch_bounds__(256) void rowmax(const int* __restrict__ mask,
        const int* __restrict__ exclk, const float* __restrict__ gum, float* __restrict__ Mr)
{
    int row = blockIdx.x, b = row >> 7, t = row & 127;
    if (t == 0 || mask[row] == 0) return;
    int k = exclk[row];
    const float* g = gum + ((size_t)k*BB + b)*NV;
    float m = -1e30f;
    for (int v = threadIdx.x; v < NV; v += 256) m = fmaxf(m, g[v]);
    __shared__ float red[256];
    red[threadIdx.x] = m; __syncthreads();
    for (int s = 128; s; s >>= 1) {
        if (threadIdx.x < s) red[threadIdx.x] = fmaxf(red[threadIdx.x], red[threadIdx.x+s]);
        __syncthreads();
    }
    if (threadIdx.x == 0) Mr[row] = red[0];
}

// ---------------- candidate scan + exact fp32 logits + argmax ----------------
__global__ __launch_bounds__(256) void cand_argmax(const int* __restrict__ mask,
        const int* __restrict__ exclk, const float* __restrict__ gum,
        const float* __restrict__ rinit, const float* __restrict__ hs,
        const float* __restrict__ Wt, const float* __restrict__ fcb,
        const float* __restrict__ Mr, const unsigned int* __restrict__ scal,
        int* __restrict__ winner)
{
    int row = blockIdx.x, b = row >> 7, t = row & 127;
    if (mask[row] == 0) return;
    int tid = threadIdx.x;
    __shared__ float red[256];
    __shared__ int idxr[256];
    __shared__ int list[256];
    __shared__ int wcnt[4];

    if (t == 0) {
        // score = rand_init[0,b,v] + gumbel[0,b,v]; full argmax
        const float* g  = gum   + (size_t)b*NV;
        const float* r0 = rinit + (size_t)b*NV;
        float bs = -1e30f; int bv = 0x7fffffff;
        for (int v = tid; v < NV; v += 256) {
            float sc = r0[v] + g[v];
            if (sc > bs) { bs = sc; bv = v; }
        }
        red[tid] = bs; idxr[tid] = bv; __syncthreads();
        for (int s = 128; s; s >>= 1) {
            if (tid < s) {
                if (red[tid+s] > red[tid] || (red[tid+s] == red[tid] && idxr[tid+s] < idxr[tid])) {
                    red[tid] = red[tid+s]; idxr[tid] = idxr[tid+s];
                }
            }
            __syncthreads();
        }
        if (tid == 0) winner[row] = idxr[0];
        return;
    }

    int k = exclk[row];
    const float* g    = gum + ((size_t)k*BB + b)*NV;
    const float* hrow = hs + ((size_t)(t-1)*BB + b)*HID;
    float bound = sqrtf(__uint_as_float(scal[0])) * sqrtf(__uint_as_float(scal[2]))
                + __uint_as_float(scal[1]);
    float thr = Mr[row] - 2.0f*bound*1.05f - 1e-6f;

    float curS = -1e30f; int curV = 0x7fffffff;   // tracked by thread 0
    int wv = tid >> 6, lane = tid & 63;
    for (int v0 = 0; v0 < NV; v0 += 256) {
        int v = v0 + tid;
        bool ok = (v < NV) && (g[v] >= thr);
        unsigned long long mb = __ballot(ok);
        if (lane == 0) wcnt[wv] = __popcll(mb);
        __syncthreads();
        int off = 0;
        #pragma unroll
        for (int w = 0; w < 4; w++) if (w < wv) off += wcnt[w];
        int tot = wcnt[0] + wcnt[1] + wcnt[2] + wcnt[3];
        if (ok) {
            int pos = off + __popcll(mb & ((1ull << lane) - 1ull));
            list[pos] = v;
        }
        __syncthreads();
        for (int ci = 0; ci < tot; ci++) {
            int vc = list[ci];
            float p = 0.f;
            for (int k2 = tid; k2 < HID; k2 += 256)
                p = fmaf(hrow[k2], Wt[(size_t)vc*HID + k2], p);
            red[tid] = p; __syncthreads();
            for (int s = 128; s; s >>= 1) {
                if (tid < s) red[tid] += red[tid+s];
                __syncthreads();
            }
            if (tid == 0) {
                float sc = (red[0] + fcb[vc]) + g[vc];
                if (sc > curS || (sc == curS && vc < curV)) { curS = sc; curV = vc; }
            }
            __syncthreads();
        }
    }
    if (tid == 0) winner[row] = curV;
}

// ---------------- write one-hot output ----------------
__global__ __launch_bounds__(256) void write_out(const int* __restrict__ winner,
                                                 float* __restrict__ out)
{
    int row = blockIdx.x;
    int win = winner[row];
    float4* o = (float4*)(out + (size_t)row*NV);
    int tid = threadIdx.x;
    #pragma unroll
    for (int i = 0; i < 10; i++) {
        int idx = tid + i*256;          // 10000/4 = 2500 float4
        if (idx < 2500) {
            int vb = idx*4;
            float4 val = {0.f, 0.f, 0.f, 0.f};
            if (win >= vb && win < vb+4) ((float*)&val)[win - vb] = 1.0f;
            o[idx] = val;
        }
    }
}

extern "C" void kernel_launch(void* const* d_in, const int* in_sizes, int n_in,
                              void* d_out, int out_size, void* d_ws, size_t ws_size,
                              hipStream_t stream)
{
    const int*   ids   = (const int*)d_in[0];
    const int*   mask  = (const int*)d_in[1];
    const float* eEmb  = (const float*)d_in[2];
    const float* eWih  = (const float*)d_in[3];
    const float* eWhh  = (const float*)d_in[4];
    const float* eB    = (const float*)d_in[5];
    const float* dEmb  = (const float*)d_in[6];
    const float* dWih  = (const float*)d_in[7];
    const float* dWhh  = (const float*)d_in[8];
    const float* dB    = (const float*)d_in[9];
    const float* fcW   = (const float*)d_in[10];
    const float* fcb   = (const float*)d_in[11];
    const float* rinit = (const float*)d_in[12];
    const float* gum   = (const float*)d_in[13];
    float* out = (float*)d_out;

    float* wsf = (float*)d_ws;
    size_t off = 0;
    float* Xenc = wsf + off; off += (size_t)TT*BB*G4;   // 8,388,608
    float* Xdec = wsf + off; off += (size_t)TD*BB*G4;   // 8,323,072
    float* h0   = wsf + off; off += BB*HID;
    float* h1   = wsf + off; off += BB*HID;
    float* cbuf = wsf + off; off += BB*HID;
    float* hs   = wsf + off; off += (size_t)TD*BB*HID;  // 2,080,768
    float* fcWt = wsf + off; off += (size_t)NV*HID;     // 5,120,000
    float* Mr   = wsf + off; off += 4096;
    unsigned int* scal = (unsigned int*)(wsf + off); off += 8;
    int* exclk  = (int*)(wsf + off); off += 4096;
    int* winner = (int*)(wsf + off); off += 4096;

    hipMemsetAsync(h0,   0, BB*HID*sizeof(float), stream);
    hipMemsetAsync(cbuf, 0, BB*HID*sizeof(float), stream);
    hipMemsetAsync(scal, 0, 8*sizeof(float), stream);

    dim3 gblk(16, 32);
    gemm_x<<<gblk, 256, 0, stream>>>(ids, eEmb, eWih, eB, Xenc, TT*BB);
    gemm_x<<<gblk, 256, 0, stream>>>(ids, dEmb, dWih, dB, Xdec, TD*BB);
    transpose_fc<<<dim3(313,16), dim3(32,8), 0, stream>>>(fcW, fcWt);
    wnorm<<<40, 256, 0, stream>>>(fcW, fcb, scal);
    routing<<<32, 128, 0, stream>>>(ids, mask, exclk, winner);

    float* hb[2] = {h0, h1};
    int cur = 0;
    for (int t = 0; t < TT; t++) {
        lstm_step<<<256, 256, 0, stream>>>(Xenc + (size_t)t*BB*G4, eWhh,
                                           hb[cur], hb[cur^1], cbuf, (float*)nullptr);
        cur ^= 1;
    }
    for (int t = 0; t < TD; t++) {
        lstm_step<<<256, 256, 0, stream>>>(Xdec + (size_t)t*BB*G4, dWhh,
                                           hb[cur], hb[cur^1], cbuf, hs + (size_t)t*BB*HID);
        cur ^= 1;
    }
    hnorm<<<TD*BB, 64, 0, stream>>>(hs, scal);
    rowmax<<<4096, 256, 0, stream>>>(mask, exclk, gum, Mr);
    cand_argmax<<<4096, 256, 0, stream>>>(mask, exclk, gum, rinit, hs, fcWt, fcb, Mr, scal, winner);
    write_out<<<4096, 256, 0, stream>>>(winner, out);
}

// Round 2
// 4976.805 us; speedup vs baseline: 1.3264x; 1.3264x over previous
//
#include <hip/hip_runtime.h>
#include <hip/hip_bf16.h>
#include <math.h>

#define BB 32
#define TT 128
#define TD 127
#define EMB 256
#define HID 512
#define G4 2048
#define NV 10000
#define NBLK 256

// ---------------- GEMM: X[m,:] = embed[tok(m)] @ W + bias ----------------
__global__ __launch_bounds__(256) void gemm_x(const int* __restrict__ ids,
        const float* __restrict__ embed, const float* __restrict__ W,
        const float* __restrict__ bias, float* __restrict__ X, int M)
{
    __shared__ float As[16][128];
    __shared__ float Bs[16][128];
    __shared__ int toks[128];
    const int tid = threadIdx.x;
    const int m0 = blockIdx.y * 128, n0 = blockIdx.x * 128;
    if (tid < 128) {
        int mr = m0 + tid, tk = 0;
        if (mr < M) { int t = mr >> 5, b = mr & 31; tk = ids[b*TT + t]; }
        toks[tid] = tk;
    }
    __syncthreads();
    float acc[8][8] = {};
    const int ty = tid >> 4, tx = tid & 15;
    for (int kt = 0; kt < EMB; kt += 16) {
        #pragma unroll
        for (int i = 0; i < 2; i++) {
            int idx = tid*2 + i;
            int row = idx >> 2, k4 = (idx & 3)*4;
            float4 a = *(const float4*)&embed[(size_t)toks[row]*EMB + kt + k4];
            As[k4+0][row] = a.x; As[k4+1][row] = a.y; As[k4+2][row] = a.z; As[k4+3][row] = a.w;
        }
        #pragma unroll
        for (int i = 0; i < 2; i++) {
            int idx = tid*2 + i;
            int kr = idx >> 5, c4 = (idx & 31)*4;
            *(float4*)&Bs[kr][c4] = *(const float4*)&W[(size_t)(kt+kr)*G4 + n0 + c4];
        }
        __syncthreads();
        #pragma unroll
        for (int k = 0; k < 16; k++) {
            float a8[8], b8[8];
            #pragma unroll
            for (int i = 0; i < 8; i++) a8[i] = As[k][ty*8+i];
            #pragma unroll
            for (int j = 0; j < 8; j++) b8[j] = Bs[k][tx*8+j];
            #pragma unroll
            for (int i = 0; i < 8; i++) {
                #pragma unroll
                for (int j = 0; j < 8; j++)
                    acc[i][j] = fmaf(a8[i], b8[j], acc[i][j]);
            }
        }
        __syncthreads();
    }
    #pragma unroll
    for (int i = 0; i < 8; i++) {
        int mr = m0 + ty*8 + i;
        if (mr < M) {
            #pragma unroll
            for (int j = 0; j < 8; j += 4) {
                int nc = n0 + tx*8 + j;
                float4 v;
                v.x = acc[i][j+0] + bias[nc+0];
                v.y = acc[i][j+1] + bias[nc+1];
                v.z = acc[i][j+2] + bias[nc+2];
                v.w = acc[i][j+3] + bias[nc+3];
                *(float4*)&X[(size_t)mr*G4 + nc] = v;
            }
        }
    }
}

// ---------------- Persistent LSTM: both phases, 255 steps, one launch ------
// 256 blocks x 512 threads. Block bid owns units {2bid, 2bid+1} (8 gate cols).
// Whh slice lives in LDS for the whole kernel. h state broadcast via L3
// (agent-scope atomics) with a device-wide counter barrier per step.
__global__ __launch_bounds__(512) void lstm_persist(
        const float* __restrict__ Xenc, const float* __restrict__ Xdec,
        const float* __restrict__ Whh_e, const float* __restrict__ Whh_d,
        float* __restrict__ hg,          // 2 * 32*512 ping-pong
        float* __restrict__ hs,          // TD*32*512
        unsigned int* __restrict__ cnt)
{
    __shared__ float sm_h[32*512];       // 64 KB, XOR-swizzled rows
    __shared__ float sm_w[8*512];        // 16 KB weight slice
    __shared__ float sm_part[512];       // [256][2] k-half partials
    __shared__ float sm_gl[256];         // activated gates [b][wl]
    __shared__ float sm_c[64];           // cell state [b][ul]

    const int tid = threadIdx.x;
    const int bid = blockIdx.x;
    const int kh = tid >> 8;             // k half
    const int r  = tid & 255;
    const int b  = r >> 3;               // batch 0..31
    const int wl = r & 7;                // local col: gate = wl>>1, ul = wl&1
    const int col = (wl >> 1)*HID + 2*bid + (wl & 1);
    const int hsw = (b & 7) << 2, wsw = wl << 2;
    const int hb = b*HID, wb = wl*HID;

    for (int i = tid; i < 32*HID; i += 512) sm_h[i] = 0.f;
    if (tid < 64) sm_c[tid] = 0.f;
    for (int i = tid; i < 8*HID; i += 512) {          // stage encoder Whh slice
        int w2 = i & 7, k = i >> 3;
        int c2 = (w2 >> 1)*HID + 2*bid + (w2 & 1);
        sm_w[w2*HID + (k ^ (w2 << 2))] = Whh_e[(size_t)k*G4 + c2];
    }
    __syncthreads();

    for (int gstep = 0; gstep < TT + TD; ++gstep) {
        const bool enc = gstep < TT;
        const int t = enc ? gstep : gstep - TT;
        const float* Xt = (enc ? Xenc : Xdec) + (size_t)t*BB*G4;
        float xv = 0.f;
        if (kh == 0) xv = Xt[b*G4 + col];
        float4 a4 = {0.f, 0.f, 0.f, 0.f};
        const int k0 = kh << 8;
        #pragma unroll 4
        for (int k = k0; k < k0 + 256; k += 4) {
            float4 hv = *(const float4*)&sm_h[hb + (k ^ hsw)];
            float4 wv = *(const float4*)&sm_w[wb + (k ^ wsw)];
            a4.x = fmaf(hv.x, wv.x, a4.x);
            a4.y = fmaf(hv.y, wv.y, a4.y);
            a4.z = fmaf(hv.z, wv.z, a4.z);
            a4.w = fmaf(hv.w, wv.w, a4.w);
        }
        sm_part[r*2 + kh] = (a4.x + a4.y) + (a4.z + a4.w);
        __syncthreads();
        if (kh == 0) {
            float gv = xv + sm_part[r*2] + sm_part[r*2 + 1];
            sm_gl[r] = ((wl >> 1) == 2) ? tanhf(gv) : 1.f/(1.f + expf(-gv));
        }
        __syncthreads();
        if (tid < 32) {
            int bq = tid;
            float h2[2];
            #pragma unroll
            for (int ul = 0; ul < 2; ++ul) {
                float i_s = sm_gl[bq*8 + 0 + ul];
                float f_s = sm_gl[bq*8 + 2 + ul];
                float g_t = sm_gl[bq*8 + 4 + ul];
                float o_s = sm_gl[bq*8 + 6 + ul];
                float cp  = sm_c[bq*2 + ul];
                float cn  = fmaf(f_s, cp, i_s * g_t);
                sm_c[bq*2 + ul] = cn;
                h2[ul] = o_s * tanhf(cn);
            }
            union { unsigned long long u; float f[2]; } pk;
            pk.f[0] = h2[0]; pk.f[1] = h2[1];
            float* hw = hg + (size_t)((gstep + 1) & 1)*BB*HID + bq*HID + 2*bid;
            __hip_atomic_store((unsigned long long*)hw, pk.u,
                               __ATOMIC_RELAXED, __HIP_MEMORY_SCOPE_AGENT);
            if (!enc) {
                hs[(size_t)t*BB*HID + bq*HID + 2*bid]     = h2[0];
                hs[(size_t)t*BB*HID + bq*HID + 2*bid + 1] = h2[1];
            }
        }
        if (gstep == TT + TD - 1) break;
        __syncthreads();                 // drain h stores (vmcnt) before flag
        if (tid == 0) {
            __hip_atomic_fetch_add(cnt, 1u, __ATOMIC_RELEASE, __HIP_MEMORY_SCOPE_AGENT);
            unsigned int tgt = (unsigned)NBLK * (unsigned)(gstep + 1);
            while (__hip_atomic_load(cnt, __ATOMIC_ACQUIRE, __HIP_MEMORY_SCOPE_AGENT) < tgt)
                __builtin_amdgcn_s_sleep(2);
        }
        __syncthreads();
        {   // stage h(t+1) into LDS
            const unsigned long long* src =
                (const unsigned long long*)(hg + (size_t)((gstep + 1) & 1)*BB*HID);
            for (int i = tid; i < BB*HID/2; i += 512) {
                unsigned long long u = __hip_atomic_load((unsigned long long*)(src + i),
                                          __ATOMIC_RELAXED, __HIP_MEMORY_SCOPE_AGENT);
                union { unsigned long long uu; float f[2]; } pk2; pk2.uu = u;
                int w2 = i*2, b2 = w2 >> 9, k2 = w2 & 511;
                int ksw = k2 ^ ((b2 & 7) << 2);
                sm_h[b2*HID + ksw]     = pk2.f[0];
                sm_h[b2*HID + ksw + 1] = pk2.f[1];
            }
        }
        if (gstep == TT - 1) {           // switch to decoder weights
            for (int i = tid; i < 8*HID; i += 512) {
                int w2 = i & 7, k = i >> 3;
                int c2 = (w2 >> 1)*HID + 2*bid + (w2 & 1);
                sm_w[w2*HID + (k ^ (w2 << 2))] = Whh_d[(size_t)k*G4 + c2];
            }
        }
        __syncthreads();
    }
}

// ---------------- transpose fc_W (512 x 10000) -> (10000 x 512) ----------------
__global__ void transpose_fc(const float* __restrict__ W, float* __restrict__ Wt)
{
    __shared__ float tile[32][33];
    int v0 = blockIdx.x*32, k0 = blockIdx.y*32;
    int tx = threadIdx.x, ty = threadIdx.y;  // (32,8)
    #pragma unroll
    for (int r = 0; r < 32; r += 8) {
        int k = k0 + ty + r, v = v0 + tx;
        tile[ty+r][tx] = (v < NV) ? W[(size_t)k*NV + v] : 0.f;
    }
    __syncthreads();
    #pragma unroll
    for (int r = 0; r < 32; r += 8) {
        int v = v0 + ty + r, k = k0 + tx;
        if (v < NV) Wt[(size_t)v*HID + k] = tile[tx][ty+r];
    }
}

// ---------------- norms for rigorous logit bound ----------------
__global__ void wnorm(const float* __restrict__ W, const float* __restrict__ bvec,
                      unsigned int* __restrict__ scal)
{
    int v = blockIdx.x*256 + threadIdx.x;
    if (v < NV) {
        float s = 0.f;
        for (int k = 0; k < HID; k++) { float w = W[(size_t)k*NV + v]; s = fmaf(w, w, s); }
        atomicMax(&scal[0], __float_as_uint(s));
        atomicMax(&scal[1], __float_as_uint(fabsf(bvec[v])));
    }
}

__global__ void hnorm(const float* __restrict__ hs, unsigned int* __restrict__ scal)
{
    int r = blockIdx.x, lane = threadIdx.x;  // 64 threads
    float s = 0.f;
    for (int k = lane; k < HID; k += 64) { float x = hs[(size_t)r*HID + k]; s = fmaf(x, x, s); }
    for (int o = 32; o; o >>= 1) s += __shfl_down(s, o);
    if (lane == 0) atomicMax(&scal[2], __float_as_uint(s));
}

// ---------------- routing ----------------
__global__ void routing(const int* __restrict__ ids, const int* __restrict__ mask,
                        int* __restrict__ exclk, int* __restrict__ winner)
{
    int b = blockIdx.x;
    __shared__ int pre[TT];
    int t = threadIdx.x;
    if (t == 0) { int s = 0; for (int i = 0; i < TT; i++) { pre[i] = s; s += mask[b*TT+i]; } }
    __syncthreads();
    exclk[b*TT + t] = pre[t];
    if (mask[b*TT + t] == 0) winner[b*TT + t] = ids[b*TT + t];
}

// ---------------- per-row gumbel max ----------------
__global__ __launch_bounds__(256) void rowmax(const int* __restrict__ mask,
        const int* __restrict__ exclk, const float* __restrict__ gum, float* __restrict__ Mr)
{
    int row = blockIdx.x, b = row >> 7, t = row & 127;
    if (t == 0 || mask[row] == 0) return;
    int k = exclk[row];
    const float* g = gum + ((size_t)k*BB + b)*NV;
    float m = -1e30f;
    for (int v = threadIdx.x; v < NV; v += 256) m = fmaxf(m, g[v]);
    __shared__ float red[256];
    red[threadIdx.x] = m; __syncthreads();
    for (int s = 128; s; s >>= 1) {
        if (threadIdx.x < s) red[threadIdx.x] = fmaxf(red[threadIdx.x], red[threadIdx.x+s]);
        __syncthreads();
    }
    if (threadIdx.x == 0) Mr[row] = red[0];
}

// ---------------- candidate scan + exact fp32 logits + argmax ----------------
__global__ __launch_bounds__(256) void cand_argmax(const int* __restrict__ mask,
        const int* __restrict__ exclk, const float* __restrict__ gum,
        const float* __restrict__ rinit, const float* __restrict__ hs,
        const float* __restrict__ Wt, const float* __restrict__ fcb,
        const float* __restrict__ Mr, const unsigned int* __restrict__ scal,
        int* __restrict__ winner)
{
    int row = blockIdx.x, b = row >> 7, t = row & 127;
    if (mask[row] == 0) return;
    int tid = threadIdx.x;
    __shared__ float red[256];
    __shared__ int idxr[256];
    __shared__ int list[256];
    __shared__ int wcnt[4];

    if (t == 0) {
        const float* g  = gum   + (size_t)b*NV;
        const float* r0 = rinit + (size_t)b*NV;
        float bs = -1e30f; int bv = 0x7fffffff;
        for (int v = tid; v < NV; v += 256) {
            float sc = r0[v] + g[v];
            if (sc > bs) { bs = sc; bv = v; }
        }
        red[tid] = bs; idxr[tid] = bv; __syncthreads();
        for (int s = 128; s; s >>= 1) {
            if (tid < s) {
                if (red[tid+s] > red[tid] || (red[tid+s] == red[tid] && idxr[tid+s] < idxr[tid])) {
                    red[tid] = red[tid+s]; idxr[tid] = idxr[tid+s];
                }
            }
            __syncthreads();
        }
        if (tid == 0) winner[row] = idxr[0];
        return;
    }

    int k = exclk[row];
    const float* g    = gum + ((size_t)k*BB + b)*NV;
    const float* hrow = hs + ((size_t)(t-1)*BB + b)*HID;
    float bound = sqrtf(__uint_as_float(scal[0])) * sqrtf(__uint_as_float(scal[2]))
                + __uint_as_float(scal[1]);
    float thr = Mr[row] - 2.0f*bound*1.05f - 1e-6f;

    float curS = -1e30f; int curV = 0x7fffffff;
    int wv = tid >> 6, lane = tid & 63;
    for (int v0 = 0; v0 < NV; v0 += 256) {
        int v = v0 + tid;
        bool ok = (v < NV) && (g[v] >= thr);
        unsigned long long mb = __ballot(ok);
        if (lane == 0) wcnt[wv] = __popcll(mb);
        __syncthreads();
        int off = 0;
        #pragma unroll
        for (int w = 0; w < 4; w++) if (w < wv) off += wcnt[w];
        int tot = wcnt[0] + wcnt[1] + wcnt[2] + wcnt[3];
        if (ok) {
            int pos = off + __popcll(mb & ((1ull << lane) - 1ull));
            list[pos] = v;
        }
        __syncthreads();
        for (int ci = 0; ci < tot; ci++) {
            int vc = list[ci];
            float p = 0.f;
            for (int k2 = tid; k2 < HID; k2 += 256)
                p = fmaf(hrow[k2], Wt[(size_t)vc*HID + k2], p);
            red[tid] = p; __syncthreads();
            for (int s = 128; s; s >>= 1) {
                if (tid < s) red[tid] += red[tid+s];
                __syncthreads();
            }
            if (tid == 0) {
                float sc = (red[0] + fcb[vc]) + g[vc];
                if (sc > curS || (sc == curS && vc < curV)) { curS = sc; curV = vc; }
            }
            __syncthreads();
        }
    }
    if (tid == 0) winner[row] = curV;
}

// ---------------- write one-hot output ----------------
__global__ __launch_bounds__(256) void write_out(const int* __restrict__ winner,
                                                 float* __restrict__ out)
{
    int row = blockIdx.x;
    int win = winner[row];
    float4* o = (float4*)(out + (size_t)row*NV);
    int tid = threadIdx.x;
    #pragma unroll
    for (int i = 0; i < 10; i++) {
        int idx = tid + i*256;
        if (idx < 2500) {
            int vb = idx*4;
            float4 val = {0.f, 0.f, 0.f, 0.f};
            if (win >= vb && win < vb+4) ((float*)&val)[win - vb] = 1.0f;
            o[idx] = val;
        }
    }
}

extern "C" void kernel_launch(void* const* d_in, const int* in_sizes, int n_in,
                              void* d_out, int out_size, void* d_ws, size_t ws_size,
                              hipStream_t stream)
{
    const int*   ids   = (const int*)d_in[0];
    const int*   mask  = (const int*)d_in[1];
    const float* eEmb  = (const float*)d_in[2];
    const float* eWih  = (const float*)d_in[3];
    const float* eWhh  = (const float*)d_in[4];
    const float* eB    = (const float*)d_in[5];
    const float* dEmb  = (const float*)d_in[6];
    const float* dWih  = (const float*)d_in[7];
    const float* dWhh  = (const float*)d_in[8];
    const float* dB    = (const float*)d_in[9];
    const float* fcW   = (const float*)d_in[10];
    const float* fcb   = (const float*)d_in[11];
    const float* rinit = (const float*)d_in[12];
    const float* gum   = (const float*)d_in[13];
    float* out = (float*)d_out;

    float* wsf = (float*)d_ws;
    size_t off = 0;
    float* Xenc = wsf + off; off += (size_t)TT*BB*G4;
    float* Xdec = wsf + off; off += (size_t)TD*BB*G4;
    float* hg   = wsf + off; off += 2*BB*HID;
    float* hs   = wsf + off; off += (size_t)TD*BB*HID;
    float* fcWt = wsf + off; off += (size_t)NV*HID;
    float* Mr   = wsf + off; off += 4096;
    unsigned int* scal = (unsigned int*)(wsf + off); off += 8;
    unsigned int* cnt  = (unsigned int*)(wsf + off); off += 16;
    int* exclk  = (int*)(wsf + off); off += 4096;
    int* winner = (int*)(wsf + off); off += 4096;

    hipMemsetAsync(scal, 0, 8*sizeof(float), stream);
    hipMemsetAsync(cnt,  0, 16*sizeof(float), stream);

    dim3 gblk(16, 32);
    gemm_x<<<gblk, 256, 0, stream>>>(ids, eEmb, eWih, eB, Xenc, TT*BB);
    gemm_x<<<gblk, 256, 0, stream>>>(ids, dEmb, dWih, dB, Xdec, TD*BB);
    transpose_fc<<<dim3(313,16), dim3(32,8), 0, stream>>>(fcW, fcWt);
    wnorm<<<40, 256, 0, stream>>>(fcW, fcb, scal);
    routing<<<32, 128, 0, stream>>>(ids, mask, exclk, winner);

    lstm_persist<<<NBLK, 512, 0, stream>>>(Xenc, Xdec, eWhh, dWhh, hg, hs, cnt);

    hnorm<<<TD*BB, 64, 0, stream>>>(hs, scal);
    rowmax<<<4096, 256, 0, stream>>>(mask, exclk, gum, Mr);
    cand_argmax<<<4096, 256, 0, stream>>>(mask, exclk, gum, rinit, hs, fcWt, fcb, Mr, scal, winner);
    write_out<<<4096, 256, 0, stream>>>(winner, out);
}

// Round 3
// 4310.052 us; speedup vs baseline: 1.5316x; 1.1547x over previous
//
#include <hip/hip_runtime.h>
#include <hip/hip_bf16.h>
#include <math.h>

#define BB 32
#define TT 128
#define TD 127
#define EMB 256
#define HID 512
#define G4 2048
#define NV 10000
#define NB 128

typedef __attribute__((ext_vector_type(8))) short short8v;
typedef __attribute__((ext_vector_type(4))) float f32x4;
typedef __attribute__((ext_vector_type(4))) unsigned int u32x4;

__device__ __forceinline__ unsigned short bf16_rne(float x){
    unsigned int u = __float_as_uint(x);
    u += 0x7fffu + ((u >> 16) & 1u);
    return (unsigned short)(u >> 16);
}
__device__ __forceinline__ float bf16f(unsigned short h){
    return __uint_as_float(((unsigned int)h) << 16);
}

// ---------------- GEMM: X[t][col][b] = embed[tok] @ W + bias ----------------
__global__ __launch_bounds__(256) void gemm_x(const int* __restrict__ ids,
        const float* __restrict__ embed, const float* __restrict__ W,
        const float* __restrict__ bias, float* __restrict__ X, int M)
{
    __shared__ float As[16][128];
    __shared__ float Bs[16][128];
    __shared__ int toks[128];
    const int tid = threadIdx.x;
    const int m0 = blockIdx.y * 128, n0 = blockIdx.x * 128;
    if (tid < 128) {
        int mr = m0 + tid, tk = 0;
        if (mr < M) { int t = mr >> 5, b = mr & 31; tk = ids[b*TT + t]; }
        toks[tid] = tk;
    }
    __syncthreads();
    float acc[8][8] = {};
    const int ty = tid >> 4, tx = tid & 15;
    for (int kt = 0; kt < EMB; kt += 16) {
        #pragma unroll
        for (int i = 0; i < 2; i++) {
            int idx = tid*2 + i;
            int row = idx >> 2, k4 = (idx & 3)*4;
            float4 a = *(const float4*)&embed[(size_t)toks[row]*EMB + kt + k4];
            As[k4+0][row] = a.x; As[k4+1][row] = a.y; As[k4+2][row] = a.z; As[k4+3][row] = a.w;
        }
        #pragma unroll
        for (int i = 0; i < 2; i++) {
            int idx = tid*2 + i;
            int kr = idx >> 5, c4 = (idx & 31)*4;
            *(float4*)&Bs[kr][c4] = *(const float4*)&W[(size_t)(kt+kr)*G4 + n0 + c4];
        }
        __syncthreads();
        #pragma unroll
        for (int k = 0; k < 16; k++) {
            float a8[8], b8[8];
            #pragma unroll
            for (int i = 0; i < 8; i++) a8[i] = As[k][ty*8+i];
            #pragma unroll
            for (int j = 0; j < 8; j++) b8[j] = Bs[k][tx*8+j];
            #pragma unroll
            for (int i = 0; i < 8; i++) {
                #pragma unroll
                for (int j = 0; j < 8; j++)
                    acc[i][j] = fmaf(a8[i], b8[j], acc[i][j]);
            }
        }
        __syncthreads();
    }
    #pragma unroll
    for (int i = 0; i < 8; i++) {
        int mr = m0 + ty*8 + i;
        if (mr < M) {
            int tt = mr >> 5, bb2 = mr & 31;
            #pragma unroll
            for (int j = 0; j < 8; j++) {
                int nc = n0 + tx*8 + j;
                X[((size_t)tt*G4 + nc)*BB + bb2] = acc[i][j] + bias[nc];
            }
        }
    }
}

// ---------------- Persistent MFMA LSTM ----------------
// 128 blocks x 512 thr. Block owns 4 units -> 16 gate cols (one N-tile).
// Wave w owns K-slice [64w, 64w+64). W frags (enc+dec, hi+lo bf16) in VGPRs
// for the whole kernel. h broadcast via L3 as packed bf16 hi|lo dwords.
__global__ __launch_bounds__(512) void lstm_persist(
        const float* __restrict__ Xenc, const float* __restrict__ Xdec,
        const float* __restrict__ Whh_e, const float* __restrict__ Whh_d,
        unsigned int* __restrict__ h_pk,   // [32][512] (bf16hi | bf16lo<<16)
        float* __restrict__ hs,            // [127][32][512]
        int* __restrict__ flags)           // [128]
{
    __shared__ float smem[8192];           // 32KB: init W-stage; then partials+xbuf
    const int tid = threadIdx.x;
    const int bid = blockIdx.x;
    const int u0 = bid*4;
    const int w  = tid >> 6;
    const int l  = tid & 63;
    const int rl = l & 15;                 // A-row / B-col / C-col in tile
    const int kg = (l >> 4) * 8;
    const int kb = w*64 + kg;              // frag k base (KS adds 32)
    const int r4 = (l >> 4) * 4;           // C row base

    short8v weh0, weh1, wel0, wel1, wdh0, wdh1, wdl0, wdl1;
    #define STAGE_W(SRC) do { \
        for (int k0 = 0; k0 < 512; k0 += 128) { \
            int kloc = tid >> 2, gg = tid & 3; \
            f32x4 v = *(const f32x4*)&SRC[(size_t)(k0 + kloc)*G4 + gg*512 + u0]; \
            *(f32x4*)&smem[(k0 + kloc)*16 + gg*4] = v; \
        } \
        __syncthreads(); } while(0)
    #define BUILD_W(WH, WL, KS) do { \
        _Pragma("unroll") \
        for (int j = 0; j < 8; ++j) { \
            float wv = smem[(kb + (KS)*32 + j)*16 + rl]; \
            unsigned short hh = bf16_rne(wv); \
            WH[j] = (short)hh; \
            WL[j] = (short)bf16_rne(wv - bf16f(hh)); \
        } } while(0)
    STAGE_W(Whh_e);
    BUILD_W(weh0, wel0, 0); BUILD_W(weh1, wel1, 1);
    __syncthreads();
    STAGE_W(Whh_d);
    BUILD_W(wdh0, wdl0, 0); BUILD_W(wdh1, wdl1, 1);
    __syncthreads();

    float* partials = smem;                // [8][16][36] padded
    float* xbuf     = smem + 8*16*36;      // [32][16]
    float c_reg = 0.f;
    const int rb = tid >> 2, rul = tid & 3;

    for (int gstep = 0; gstep < TT + TD; ++gstep) {
        const bool enc = gstep < TT;
        const int t = enc ? gstep : gstep - TT;
        const float* Xt = (enc ? Xenc : Xdec) + (size_t)t*G4*BB;

        {   // stage X tile (overlaps with frag loads / MFMA issue)
            int b = tid >> 4, n = tid & 15;
            int col = (n >> 2)*512 + u0 + (n & 3);
            xbuf[b*16 + n] = Xt[(size_t)col*BB + b];
        }

        f32x4 acc0 = {0.f,0.f,0.f,0.f}, acc1 = {0.f,0.f,0.f,0.f};
        if (gstep > 0) {
            short8v ah00, ah01, ah10, ah11, al00, al01, al10, al11;
            #define LOAD_A(AH, AL, MT, KS) do { \
                const unsigned int* pp = &h_pk[(size_t)((MT)*16 + rl)*HID + kb + (KS)*32]; \
                u32x4 p0 = *(const u32x4*)pp; \
                u32x4 p1 = *(const u32x4*)(pp + 4); \
                _Pragma("unroll") \
                for (int j = 0; j < 4; ++j) { \
                    AH[j]   = (short)(p0[j] & 0xffffu); AL[j]   = (short)(p0[j] >> 16); \
                    AH[4+j] = (short)(p1[j] & 0xffffu); AL[4+j] = (short)(p1[j] >> 16); \
                } } while(0)
            LOAD_A(ah00, al00, 0, 0); LOAD_A(ah01, al01, 0, 1);
            LOAD_A(ah10, al10, 1, 0); LOAD_A(ah11, al11, 1, 1);
            #define MFMA6(ACC, AH0, AH1, AL0, AL1, WH0, WH1, WL0, WL1) do { \
                ACC = __builtin_amdgcn_mfma_f32_16x16x32_bf16(AH0, WH0, ACC, 0,0,0); \
                ACC = __builtin_amdgcn_mfma_f32_16x16x32_bf16(AH1, WH1, ACC, 0,0,0); \
                ACC = __builtin_amdgcn_mfma_f32_16x16x32_bf16(AL0, WH0, ACC, 0,0,0); \
                ACC = __builtin_amdgcn_mfma_f32_16x16x32_bf16(AL1, WH1, ACC, 0,0,0); \
                ACC = __builtin_amdgcn_mfma_f32_16x16x32_bf16(AH0, WL0, ACC, 0,0,0); \
                ACC = __builtin_amdgcn_mfma_f32_16x16x32_bf16(AH1, WL1, ACC, 0,0,0); \
            } while(0)
            if (enc) {
                MFMA6(acc0, ah00, ah01, al00, al01, weh0, weh1, wel0, wel1);
                MFMA6(acc1, ah10, ah11, al10, al11, weh0, weh1, wel0, wel1);
            } else {
                MFMA6(acc0, ah00, ah01, al00, al01, wdh0, wdh1, wdl0, wdl1);
                MFMA6(acc1, ah10, ah11, al10, al11, wdh0, wdh1, wdl0, wdl1);
            }
        }
        *(f32x4*)&partials[(w*16 + rl)*36 + r4]      = acc0;
        *(f32x4*)&partials[(w*16 + rl)*36 + 16 + r4] = acc1;
        __syncthreads();

        if (tid < 128) {
            float pre[4];
            #pragma unroll
            for (int g = 0; g < 4; ++g) {
                int n = g*4 + rul;
                float s = xbuf[rb*16 + n];
                #pragma unroll
                for (int ww = 0; ww < 8; ++ww)
                    s += partials[(ww*16 + n)*36 + rb];
                pre[g] = s;
            }
            float iv = 1.f/(1.f + expf(-pre[0]));
            float fv = 1.f/(1.f + expf(-pre[1]));
            float gv = tanhf(pre[2]);
            float ov = 1.f/(1.f + expf(-pre[3]));
            c_reg = fmaf(fv, c_reg, iv*gv);
            float hv = ov * tanhf(c_reg);
            unsigned short hh = bf16_rne(hv);
            unsigned short hl = bf16_rne(hv - bf16f(hh));
            unsigned int pk = (unsigned int)hh | ((unsigned int)hl << 16);
            __hip_atomic_store(&h_pk[(size_t)rb*HID + u0 + rul], pk,
                               __ATOMIC_RELAXED, __HIP_MEMORY_SCOPE_AGENT);
            if (!enc) hs[((size_t)t*BB + rb)*HID + u0 + rul] = hv;
        }
        __syncthreads();                  // drains all waves' stores (vmcnt 0)
        if (gstep == TT + TD - 1) break;
        if (tid == 0)
            __hip_atomic_store(&flags[bid], gstep + 1,
                               __ATOMIC_RELEASE, __HIP_MEMORY_SCOPE_AGENT);
        if (tid < NB) {
            while (__hip_atomic_load(&flags[tid], __ATOMIC_RELAXED,
                                     __HIP_MEMORY_SCOPE_AGENT) <= gstep) {}
        }
        __syncthreads();
        __builtin_amdgcn_fence(__ATOMIC_ACQUIRE, "agent");
    }
}

// ---------------- transpose fc_W (512 x 10000) -> (10000 x 512) ----------------
__global__ void transpose_fc(const float* __restrict__ W, float* __restrict__ Wt)
{
    __shared__ float tile[32][33];
    int v0 = blockIdx.x*32, k0 = blockIdx.y*32;
    int tx = threadIdx.x, ty = threadIdx.y;  // (32,8)
    #pragma unroll
    for (int r = 0; r < 32; r += 8) {
        int k = k0 + ty + r, v = v0 + tx;
        tile[ty+r][tx] = (v < NV) ? W[(size_t)k*NV + v] : 0.f;
    }
    __syncthreads();
    #pragma unroll
    for (int r = 0; r < 32; r += 8) {
        int v = v0 + ty + r, k = k0 + tx;
        if (v < NV) Wt[(size_t)v*HID + k] = tile[tx][ty+r];
    }
}

// ---------------- norms for rigorous logit bound ----------------
__global__ void wnorm(const float* __restrict__ W, const float* __restrict__ bvec,
                      unsigned int* __restrict__ scal)
{
    int v = blockIdx.x*256 + threadIdx.x;
    if (v < NV) {
        float s = 0.f;
        for (int k = 0; k < HID; k++) { float w = W[(size_t)k*NV + v]; s = fmaf(w, w, s); }
        atomicMax(&scal[0], __float_as_uint(s));
        atomicMax(&scal[1], __float_as_uint(fabsf(bvec[v])));
    }
}

__global__ void hnorm(const float* __restrict__ hs, unsigned int* __restrict__ scal)
{
    int r = blockIdx.x, lane = threadIdx.x;  // 64 threads
    float s = 0.f;
    for (int k = lane; k < HID; k += 64) { float x = hs[(size_t)r*HID + k]; s = fmaf(x, x, s); }
    for (int o = 32; o; o >>= 1) s += __shfl_down(s, o);
    if (lane == 0) atomicMax(&scal[2], __float_as_uint(s));
}

// ---------------- routing ----------------
__global__ void routing(const int* __restrict__ ids, const int* __restrict__ mask,
                        int* __restrict__ exclk, int* __restrict__ winner)
{
    int b = blockIdx.x;
    __shared__ int pre[TT];
    int t = threadIdx.x;
    if (t == 0) { int s = 0; for (int i = 0; i < TT; i++) { pre[i] = s; s += mask[b*TT+i]; } }
    __syncthreads();
    exclk[b*TT + t] = pre[t];
    if (mask[b*TT + t] == 0) winner[b*TT + t] = ids[b*TT + t];
}

// ---------------- per-row gumbel max ----------------
__global__ __launch_bounds__(256) void rowmax(const int* __restrict__ mask,
        const int* __restrict__ exclk, const float* __restrict__ gum, float* __restrict__ Mr)
{
    int row = blockIdx.x, b = row >> 7, t = row & 127;
    if (t == 0 || mask[row] == 0) return;
    int k = exclk[row];
    const float* g = gum + ((size_t)k*BB + b)*NV;
    float m = -1e30f;
    for (int v = threadIdx.x; v < NV; v += 256) m = fmaxf(m, g[v]);
    __shared__ float red[256];
    red[threadIdx.x] = m; __syncthreads();
    for (int s = 128; s; s >>= 1) {
        if (threadIdx.x < s) red[threadIdx.x] = fmaxf(red[threadIdx.x], red[threadIdx.x+s]);
        __syncthreads();
    }
    if (threadIdx.x == 0) Mr[row] = red[0];
}

// ---------------- candidate scan + exact fp32 logits + argmax ----------------
__global__ __launch_bounds__(256) void cand_argmax(const int* __restrict__ mask,
        const int* __restrict__ exclk, const float* __restrict__ gum,
        const float* __restrict__ rinit, const float* __restrict__ hs,
        const float* __restrict__ Wt, const float* __restrict__ fcb,
        const float* __restrict__ Mr, const unsigned int* __restrict__ scal,
        int* __restrict__ winner)
{
    int row = blockIdx.x, b = row >> 7, t = row & 127;
    if (mask[row] == 0) return;
    int tid = threadIdx.x;
    __shared__ float red[256];
    __shared__ int idxr[256];
    __shared__ int list[256];
    __shared__ int wcnt[4];

    if (t == 0) {
        const float* g  = gum   + (size_t)b*NV;
        const float* r0 = rinit + (size_t)b*NV;
        float bs = -1e30f; int bv = 0x7fffffff;
        for (int v = tid; v < NV; v += 256) {
            float sc = r0[v] + g[v];
            if (sc > bs) { bs = sc; bv = v; }
        }
        red[tid] = bs; idxr[tid] = bv; __syncthreads();
        for (int s = 128; s; s >>= 1) {
            if (tid < s) {
                if (red[tid+s] > red[tid] || (red[tid+s] == red[tid] && idxr[tid+s] < idxr[tid])) {
                    red[tid] = red[tid+s]; idxr[tid] = idxr[tid+s];
                }
            }
            __syncthreads();
        }
        if (tid == 0) winner[row] = idxr[0];
        return;
    }

    int k = exclk[row];
    const float* g    = gum + ((size_t)k*BB + b)*NV;
    const float* hrow = hs + ((size_t)(t-1)*BB + b)*HID;
    float bound = sqrtf(__uint_as_float(scal[0])) * sqrtf(__uint_as_float(scal[2]))
                + __uint_as_float(scal[1]);
    float thr = Mr[row] - 2.0f*bound*1.05f - 1e-6f;

    float curS = -1e30f; int curV = 0x7fffffff;
    int wv = tid >> 6, lane = tid & 63;
    for (int v0 = 0; v0 < NV; v0 += 256) {
        int v = v0 + tid;
        bool ok = (v < NV) && (g[v] >= thr);
        unsigned long long mb = __ballot(ok);
        if (lane == 0) wcnt[wv] = __popcll(mb);
        __syncthreads();
        int off = 0;
        #pragma unroll
        for (int w = 0; w < 4; w++) if (w < wv) off += wcnt[w];
        int tot = wcnt[0] + wcnt[1] + wcnt[2] + wcnt[3];
        if (ok) {
            int pos = off + __popcll(mb & ((1ull << lane) - 1ull));
            list[pos] = v;
        }
        __syncthreads();
        for (int ci = 0; ci < tot; ci++) {
            int vc = list[ci];
            float p = 0.f;
            for (int k2 = tid; k2 < HID; k2 += 256)
                p = fmaf(hrow[k2], Wt[(size_t)vc*HID + k2], p);
            red[tid] = p; __syncthreads();
            for (int s = 128; s; s >>= 1) {
                if (tid < s) red[tid] += red[tid+s];
                __syncthreads();
            }
            if (tid == 0) {
                float sc = (red[0] + fcb[vc]) + g[vc];
                if (sc > curS || (sc == curS && vc < curV)) { curS = sc; curV = vc; }
            }
            __syncthreads();
        }
    }
    if (tid == 0) winner[row] = curV;
}

// ---------------- write one-hot output ----------------
__global__ __launch_bounds__(256) void write_out(const int* __restrict__ winner,
                                                 float* __restrict__ out)
{
    int row = blockIdx.x;
    int win = winner[row];
    float4* o = (float4*)(out + (size_t)row*NV);
    int tid = threadIdx.x;
    #pragma unroll
    for (int i = 0; i < 10; i++) {
        int idx = tid + i*256;
        if (idx < 2500) {
            int vb = idx*4;
            float4 val = {0.f, 0.f, 0.f, 0.f};
            if (win >= vb && win < vb+4) ((float*)&val)[win - vb] = 1.0f;
            o[idx] = val;
        }
    }
}

extern "C" void kernel_launch(void* const* d_in, const int* in_sizes, int n_in,
                              void* d_out, int out_size, void* d_ws, size_t ws_size,
                              hipStream_t stream)
{
    const int*   ids   = (const int*)d_in[0];
    const int*   mask  = (const int*)d_in[1];
    const float* eEmb  = (const float*)d_in[2];
    const float* eWih  = (const float*)d_in[3];
    const float* eWhh  = (const float*)d_in[4];
    const float* eB    = (const float*)d_in[5];
    const float* dEmb  = (const float*)d_in[6];
    const float* dWih  = (const float*)d_in[7];
    const float* dWhh  = (const float*)d_in[8];
    const float* dB    = (const float*)d_in[9];
    const float* fcW   = (const float*)d_in[10];
    const float* fcb   = (const float*)d_in[11];
    const float* rinit = (const float*)d_in[12];
    const float* gum   = (const float*)d_in[13];
    float* out = (float*)d_out;

    float* wsf = (float*)d_ws;
    size_t off = 0;
    float* Xenc = wsf + off; off += (size_t)TT*BB*G4;      // [t][col][b]
    float* Xdec = wsf + off; off += (size_t)TD*BB*G4;
    unsigned int* h_pk = (unsigned int*)(wsf + off); off += (size_t)BB*HID;
    float* hs   = wsf + off; off += (size_t)TD*BB*HID;
    float* fcWt = wsf + off; off += (size_t)NV*HID;
    float* Mr   = wsf + off; off += 4096;
    unsigned int* scal = (unsigned int*)(wsf + off); off += 8;
    int* flags  = (int*)(wsf + off); off += NB;
    int* exclk  = (int*)(wsf + off); off += 4096;
    int* winner = (int*)(wsf + off); off += 4096;

    hipMemsetAsync(scal,  0, 8*sizeof(int), stream);
    hipMemsetAsync(flags, 0, NB*sizeof(int), stream);

    dim3 gblk(16, 32);
    gemm_x<<<gblk, 256, 0, stream>>>(ids, eEmb, eWih, eB, Xenc, TT*BB);
    gemm_x<<<gblk, 256, 0, stream>>>(ids, dEmb, dWih, dB, Xdec, TD*BB);
    transpose_fc<<<dim3(313,16), dim3(32,8), 0, stream>>>(fcW, fcWt);
    wnorm<<<40, 256, 0, stream>>>(fcW, fcb, scal);
    routing<<<32, 128, 0, stream>>>(ids, mask, exclk, winner);

    lstm_persist<<<NB, 512, 0, stream>>>(Xenc, Xdec, eWhh, dWhh, h_pk, hs, flags);

    hnorm<<<TD*BB, 64, 0, stream>>>(hs, scal);
    rowmax<<<4096, 256, 0, stream>>>(mask, exclk, gum, Mr);
    cand_argmax<<<4096, 256, 0, stream>>>(mask, exclk, gum, rinit, hs, fcWt, fcb, Mr, scal, winner);
    write_out<<<4096, 256, 0, stream>>>(winner, out);
}

// Round 4
// 1853.365 us; speedup vs baseline: 3.5618x; 2.3255x over previous
//
#include <hip/hip_runtime.h>
#include <hip/hip_bf16.h>
#include <math.h>

#define BB 32
#define TT 128
#define TD 127
#define EMB 256
#define HID 512
#define G4 2048
#define NV 10000
#define NB 64
#define UPB 8      // units per block -> 32 gate cols

typedef __attribute__((ext_vector_type(8))) short short8v;
typedef __attribute__((ext_vector_type(4))) float f32x4;

__device__ __forceinline__ unsigned short bf16_rne(float x){
    unsigned int u = __float_as_uint(x);
    u += 0x7fffu + ((u >> 16) & 1u);
    return (unsigned short)(u >> 16);
}
__device__ __forceinline__ float bf16f(unsigned short h){
    return __uint_as_float(((unsigned int)h) << 16);
}

// ---------------- GEMM: X[t][col][b] = embed[tok] @ W + bias ----------------
__global__ __launch_bounds__(256) void gemm_x(const int* __restrict__ ids,
        const float* __restrict__ embed, const float* __restrict__ W,
        const float* __restrict__ bias, float* __restrict__ X, int M)
{
    __shared__ float As[16][128];
    __shared__ float Bs[16][128];
    __shared__ int toks[128];
    const int tid = threadIdx.x;
    const int m0 = blockIdx.y * 128, n0 = blockIdx.x * 128;
    if (tid < 128) {
        int mr = m0 + tid, tk = 0;
        if (mr < M) { int t = mr >> 5, b = mr & 31; tk = ids[b*TT + t]; }
        toks[tid] = tk;
    }
    __syncthreads();
    float acc[8][8] = {};
    const int ty = tid >> 4, tx = tid & 15;
    for (int kt = 0; kt < EMB; kt += 16) {
        #pragma unroll
        for (int i = 0; i < 2; i++) {
            int idx = tid*2 + i;
            int row = idx >> 2, k4 = (idx & 3)*4;
            float4 a = *(const float4*)&embed[(size_t)toks[row]*EMB + kt + k4];
            As[k4+0][row] = a.x; As[k4+1][row] = a.y; As[k4+2][row] = a.z; As[k4+3][row] = a.w;
        }
        #pragma unroll
        for (int i = 0; i < 2; i++) {
            int idx = tid*2 + i;
            int kr = idx >> 5, c4 = (idx & 31)*4;
            *(float4*)&Bs[kr][c4] = *(const float4*)&W[(size_t)(kt+kr)*G4 + n0 + c4];
        }
        __syncthreads();
        #pragma unroll
        for (int k = 0; k < 16; k++) {
            float a8[8], b8[8];
            #pragma unroll
            for (int i = 0; i < 8; i++) a8[i] = As[k][ty*8+i];
            #pragma unroll
            for (int j = 0; j < 8; j++) b8[j] = Bs[k][tx*8+j];
            #pragma unroll
            for (int i = 0; i < 8; i++) {
                #pragma unroll
                for (int j = 0; j < 8; j++)
                    acc[i][j] = fmaf(a8[i], b8[j], acc[i][j]);
            }
        }
        __syncthreads();
    }
    #pragma unroll
    for (int i = 0; i < 8; i++) {
        int mr = m0 + ty*8 + i;
        if (mr < M) {
            int tt = mr >> 5, bb2 = mr & 31;
            #pragma unroll
            for (int j = 0; j < 8; j++) {
                int nc = n0 + tx*8 + j;
                X[((size_t)tt*G4 + nc)*BB + bb2] = acc[i][j] + bias[nc];
            }
        }
    }
}

// ---------------- Persistent MFMA LSTM ----------------
// 64 blocks x 512 thr (8 waves). Block owns 8 units -> 32 gate cols (2 N-tiles).
// Wave w: K-slice [64w, 64w+64). W frags rebuilt per phase, live in VGPRs.
// h exchange: ping-pong [2][512 units][32 batch] packed bf16 hi|lo dwords via
// sc1 (agent-scope) atomics; flag-array barrier; NO fences in the loop.
__global__ __launch_bounds__(512) void lstm_persist(
        const float* __restrict__ Xenc, const float* __restrict__ Xdec,
        const float* __restrict__ Whh_e, const float* __restrict__ Whh_d,
        unsigned int* __restrict__ h_pk,   // [2][512][32]
        float* __restrict__ hs,            // [127][32][512]
        int* __restrict__ flags)           // [64]
{
    __shared__ float smem[10272];          // partials [8][32][36] + xbuf [32][33]
    float* partials = smem;                // 9216 floats (also W-stage scratch)
    float* xbuf     = smem + 9216;         // 1056 floats

    const int tid = threadIdx.x;
    const int bid = blockIdx.x;
    const int u0  = bid*UPB;
    const int w   = tid >> 6;
    const int l   = tid & 63;
    const int rl  = l & 15;                // A-row / B-col / C-col in tile
    const int kg  = (l >> 4) * 8;          // frag k sub-base
    const int r4  = (l >> 4) * 4;          // C row base

    short8v wH_n0k0, wH_n0k1, wH_n1k0, wH_n1k1;
    short8v wL_n0k0, wL_n0k1, wL_n1k0, wL_n1k1;

    #define BW(WH, WL, KB, CO) do { _Pragma("unroll") \
        for (int j = 0; j < 8; ++j) { \
            float wv = partials[((KB)+j)*32 + (CO) + rl]; \
            unsigned short h2 = bf16_rne(wv); \
            WH[j] = (short)h2; \
            WL[j] = (short)bf16_rne(wv - bf16f(h2)); \
        } } while(0)

    #define STAGE_BUILD(SRC) do { \
        for (int c = 0; c < 4; ++c) { \
            int k0 = c*128; \
            __syncthreads(); \
            for (int i = tid; i < 4096; i += 512) { \
                int kl = i >> 5, n = i & 31; \
                partials[kl*32 + n] = SRC[(size_t)(k0+kl)*G4 + (size_t)((n>>3)*512 + u0 + (n&7))]; \
            } \
            __syncthreads(); \
            if ((w >> 1) == c) { \
                int kb0 = w*64 - k0 + kg; \
                BW(wH_n0k0, wL_n0k0, kb0,      0); \
                BW(wH_n0k1, wL_n0k1, kb0 + 32, 0); \
                BW(wH_n1k0, wL_n1k0, kb0,     16); \
                BW(wH_n1k1, wL_n1k1, kb0 + 32,16); \
            } \
        } \
        __syncthreads(); } while(0)

    STAGE_BUILD(Whh_e);

    {   // prologue: stage X tile for step 0
        for (int i = tid; i < 1024; i += 512) {
            int row = i & 31, n = i >> 5;
            xbuf[row*33 + n] = Xenc[(size_t)((n>>3)*512 + u0 + (n&7))*32 + row];
        }
        __syncthreads();
    }

    float c_reg = 0.f;
    const int gb = tid >> 3, gul = tid & 7;    // gate-thread mapping (tid<256)

    for (int gstep = 0; gstep < TT + TD; ++gstep) {
        const bool enc = gstep < TT;
        const int t = enc ? gstep : gstep - TT;

        f32x4 acc00 = {0,0,0,0}, acc01 = {0,0,0,0}, acc10 = {0,0,0,0}, acc11 = {0,0,0,0};
        if (gstep > 0) {
            const unsigned int* hp = h_pk + (size_t)(gstep & 1)*16384;
            short8v aH_m0k0, aH_m0k1, aH_m1k0, aH_m1k1;
            short8v aL_m0k0, aL_m0k1, aL_m1k0, aL_m1k1;
            #define LOAD_A(AH, AL, MT, KS) do { \
                unsigned int pv[8]; \
                int kbase = w*64 + (KS)*32 + kg; \
                int brow = (MT)*16 + rl; \
                _Pragma("unroll") \
                for (int j = 0; j < 8; ++j) \
                    pv[j] = __hip_atomic_load(&hp[(kbase+j)*32 + brow], \
                                __ATOMIC_RELAXED, __HIP_MEMORY_SCOPE_AGENT); \
                _Pragma("unroll") \
                for (int j = 0; j < 8; ++j) { \
                    AH[j] = (short)(pv[j] & 0xffffu); \
                    AL[j] = (short)(pv[j] >> 16); \
                } } while(0)
            LOAD_A(aH_m0k0, aL_m0k0, 0, 0); LOAD_A(aH_m0k1, aL_m0k1, 0, 1);
            LOAD_A(aH_m1k0, aL_m1k0, 1, 0); LOAD_A(aH_m1k1, aL_m1k1, 1, 1);
            #define MM6(ACC, AH0, AH1, AL0, AL1, WH0, WH1, WL0, WL1) do { \
                ACC = __builtin_amdgcn_mfma_f32_16x16x32_bf16(AH0, WH0, ACC, 0,0,0); \
                ACC = __builtin_amdgcn_mfma_f32_16x16x32_bf16(AH1, WH1, ACC, 0,0,0); \
                ACC = __builtin_amdgcn_mfma_f32_16x16x32_bf16(AL0, WH0, ACC, 0,0,0); \
                ACC = __builtin_amdgcn_mfma_f32_16x16x32_bf16(AL1, WH1, ACC, 0,0,0); \
                ACC = __builtin_amdgcn_mfma_f32_16x16x32_bf16(AH0, WL0, ACC, 0,0,0); \
                ACC = __builtin_amdgcn_mfma_f32_16x16x32_bf16(AH1, WL1, ACC, 0,0,0); \
            } while(0)
            MM6(acc00, aH_m0k0, aH_m0k1, aL_m0k0, aL_m0k1, wH_n0k0, wH_n0k1, wL_n0k0, wL_n0k1);
            MM6(acc01, aH_m0k0, aH_m0k1, aL_m0k0, aL_m0k1, wH_n1k0, wH_n1k1, wL_n1k0, wL_n1k1);
            MM6(acc10, aH_m1k0, aH_m1k1, aL_m1k0, aL_m1k1, wH_n0k0, wH_n0k1, wL_n0k0, wL_n0k1);
            MM6(acc11, aH_m1k0, aH_m1k1, aL_m1k0, aL_m1k1, wH_n1k0, wH_n1k1, wL_n1k0, wL_n1k1);
        }
        // C -> LDS partials [w][row32][col32+pad]
        #pragma unroll
        for (int j = 0; j < 4; ++j) {
            partials[(w*32 +      r4 + j)*36 +      rl] = acc00[j];
            partials[(w*32 +      r4 + j)*36 + 16 + rl] = acc01[j];
            partials[(w*32 + 16 + r4 + j)*36 +      rl] = acc10[j];
            partials[(w*32 + 16 + r4 + j)*36 + 16 + rl] = acc11[j];
        }
        __syncthreads();

        if (tid < 256) {
            float pre[4];
            #pragma unroll
            for (int g = 0; g < 4; ++g) {
                float s = xbuf[gb*33 + g*8 + gul];
                #pragma unroll
                for (int ww = 0; ww < 8; ++ww)
                    s += partials[(ww*32 + gb)*36 + g*8 + gul];
                pre[g] = s;
            }
            float iv = 1.f/(1.f + expf(-pre[0]));
            float fv = 1.f/(1.f + expf(-pre[1]));
            float gv = tanhf(pre[2]);
            float ov = 1.f/(1.f + expf(-pre[3]));
            c_reg = fmaf(fv, c_reg, iv*gv);
            float hv = ov * tanhf(c_reg);
            unsigned short hh = bf16_rne(hv);
            unsigned short hl = bf16_rne(hv - bf16f(hh));
            unsigned int pk = (unsigned int)hh | ((unsigned int)hl << 16);
            __hip_atomic_store(&h_pk[(size_t)((gstep+1) & 1)*16384 + (u0+gul)*32 + gb],
                               pk, __ATOMIC_RELAXED, __HIP_MEMORY_SCOPE_AGENT);
            if (!enc) hs[((size_t)t*BB + gb)*HID + u0 + gul] = hv;
        }
        __syncthreads();                   // all waves' stores drained (vmcnt 0)
        if (gstep == TT + TD - 1) break;

        if (gstep == TT - 1) STAGE_BUILD(Whh_d);   // phase switch (uniform)

        {   // stage X for next step (overlaps the poll wait)
            int tn = gstep + 1 < TT ? gstep + 1 : gstep + 1 - TT;
            const float* Xt = (gstep + 1 < TT ? Xenc : Xdec) + (size_t)tn*G4*BB;
            for (int i = tid; i < 1024; i += 512) {
                int row = i & 31, n = i >> 5;
                xbuf[row*33 + n] = Xt[(size_t)((n>>3)*512 + u0 + (n&7))*32 + row];
            }
        }
        if (tid == 0)
            __hip_atomic_store(&flags[bid], gstep + 1,
                               __ATOMIC_RELEASE, __HIP_MEMORY_SCOPE_AGENT);
        if (tid < NB) {
            while (__hip_atomic_load(&flags[tid], __ATOMIC_RELAXED,
                                     __HIP_MEMORY_SCOPE_AGENT) <= gstep) {}
        }
        __syncthreads();
        asm volatile("" ::: "memory");
    }
}

// ---------------- transpose fc_W (512 x 10000) -> (10000 x 512) ----------------
__global__ void transpose_fc(const float* __restrict__ W, float* __restrict__ Wt)
{
    __shared__ float tile[32][33];
    int v0 = blockIdx.x*32, k0 = blockIdx.y*32;
    int tx = threadIdx.x, ty = threadIdx.y;  // (32,8)
    #pragma unroll
    for (int r = 0; r < 32; r += 8) {
        int k = k0 + ty + r, v = v0 + tx;
        tile[ty+r][tx] = (v < NV) ? W[(size_t)k*NV + v] : 0.f;
    }
    __syncthreads();
    #pragma unroll
    for (int r = 0; r < 32; r += 8) {
        int v = v0 + ty + r, k = k0 + tx;
        if (v < NV) Wt[(size_t)v*HID + k] = tile[tx][ty+r];
    }
}

// ---------------- norms for rigorous logit bound ----------------
__global__ void wnorm(const float* __restrict__ W, const float* __restrict__ bvec,
                      unsigned int* __restrict__ scal)
{
    int v = blockIdx.x*256 + threadIdx.x;
    if (v < NV) {
        float s = 0.f;
        for (int k = 0; k < HID; k++) { float w = W[(size_t)k*NV + v]; s = fmaf(w, w, s); }
        atomicMax(&scal[0], __float_as_uint(s));
        atomicMax(&scal[1], __float_as_uint(fabsf(bvec[v])));
    }
}

__global__ void hnorm(const float* __restrict__ hs, unsigned int* __restrict__ scal)
{
    int r = blockIdx.x, lane = threadIdx.x;  // 64 threads
    float s = 0.f;
    for (int k = lane; k < HID; k += 64) { float x = hs[(size_t)r*HID + k]; s = fmaf(x, x, s); }
    for (int o = 32; o; o >>= 1) s += __shfl_down(s, o);
    if (lane == 0) atomicMax(&scal[2], __float_as_uint(s));
}

// ---------------- routing ----------------
__global__ void routing(const int* __restrict__ ids, const int* __restrict__ mask,
                        int* __restrict__ exclk, int* __restrict__ winner)
{
    int b = blockIdx.x;
    __shared__ int pre[TT];
    int t = threadIdx.x;
    if (t == 0) { int s = 0; for (int i = 0; i < TT; i++) { pre[i] = s; s += mask[b*TT+i]; } }
    __syncthreads();
    exclk[b*TT + t] = pre[t];
    if (mask[b*TT + t] == 0) winner[b*TT + t] = ids[b*TT + t];
}

// ---------------- per-row gumbel max ----------------
__global__ __launch_bounds__(256) void rowmax(const int* __restrict__ mask,
        const int* __restrict__ exclk, const float* __restrict__ gum, float* __restrict__ Mr)
{
    int row = blockIdx.x, b = row >> 7, t = row & 127;
    if (t == 0 || mask[row] == 0) return;
    int k = exclk[row];
    const float* g = gum + ((size_t)k*BB + b)*NV;
    float m = -1e30f;
    for (int v = threadIdx.x; v < NV; v += 256) m = fmaxf(m, g[v]);
    __shared__ float red[256];
    red[threadIdx.x] = m; __syncthreads();
    for (int s = 128; s; s >>= 1) {
        if (threadIdx.x < s) red[threadIdx.x] = fmaxf(red[threadIdx.x], red[threadIdx.x+s]);
        __syncthreads();
    }
    if (threadIdx.x == 0) Mr[row] = red[0];
}

// ---------------- candidate scan + exact fp32 logits + argmax ----------------
__global__ __launch_bounds__(256) void cand_argmax(const int* __restrict__ mask,
        const int* __restrict__ exclk, const float* __restrict__ gum,
        const float* __restrict__ rinit, const float* __restrict__ hs,
        const float* __restrict__ Wt, const float* __restrict__ fcb,
        const float* __restrict__ Mr, const unsigned int* __restrict__ scal,
        int* __restrict__ winner)
{
    int row = blockIdx.x, b = row >> 7, t = row & 127;
    if (mask[row] == 0) return;
    int tid = threadIdx.x;
    __shared__ float red[256];
    __shared__ int idxr[256];
    __shared__ int list[256];
    __shared__ int wcnt[4];

    if (t == 0) {
        const float* g  = gum   + (size_t)b*NV;
        const float* r0 = rinit + (size_t)b*NV;
        float bs = -1e30f; int bv = 0x7fffffff;
        for (int v = tid; v < NV; v += 256) {
            float sc = r0[v] + g[v];
            if (sc > bs) { bs = sc; bv = v; }
        }
        red[tid] = bs; idxr[tid] = bv; __syncthreads();
        for (int s = 128; s; s >>= 1) {
            if (tid < s) {
                if (red[tid+s] > red[tid] || (red[tid+s] == red[tid] && idxr[tid+s] < idxr[tid])) {
                    red[tid] = red[tid+s]; idxr[tid] = idxr[tid+s];
                }
            }
            __syncthreads();
        }
        if (tid == 0) winner[row] = idxr[0];
        return;
    }

    int k = exclk[row];
    const float* g    = gum + ((size_t)k*BB + b)*NV;
    const float* hrow = hs + ((size_t)(t-1)*BB + b)*HID;
    float bound = sqrtf(__uint_as_float(scal[0])) * sqrtf(__uint_as_float(scal[2]))
                + __uint_as_float(scal[1]);
    float thr = Mr[row] - 2.0f*bound*1.05f - 1e-6f;

    float curS = -1e30f; int curV = 0x7fffffff;
    int wv = tid >> 6, lane = tid & 63;
    for (int v0 = 0; v0 < NV; v0 += 256) {
        int v = v0 + tid;
        bool ok = (v < NV) && (g[v] >= thr);
        unsigned long long mb = __ballot(ok);
        if (lane == 0) wcnt[wv] = __popcll(mb);
        __syncthreads();
        int off = 0;
        #pragma unroll
        for (int w = 0; w < 4; w++) if (w < wv) off += wcnt[w];
        int tot = wcnt[0] + wcnt[1] + wcnt[2] + wcnt[3];
        if (ok) {
            int pos = off + __popcll(mb & ((1ull << lane) - 1ull));
            list[pos] = v;
        }
        __syncthreads();
        for (int ci = 0; ci < tot; ci++) {
            int vc = list[ci];
            float p = 0.f;
            for (int k2 = tid; k2 < HID; k2 += 256)
                p = fmaf(hrow[k2], Wt[(size_t)vc*HID + k2], p);
            red[tid] = p; __syncthreads();
            for (int s = 128; s; s >>= 1) {
                if (tid < s) red[tid] += red[tid+s];
                __syncthreads();
            }
            if (tid == 0) {
                float sc = (red[0] + fcb[vc]) + g[vc];
                if (sc > curS || (sc == curS && vc < curV)) { curS = sc; curV = vc; }
            }
            __syncthreads();
        }
    }
    if (tid == 0) winner[row] = curV;
}

// ---------------- write one-hot output ----------------
__global__ __launch_bounds__(256) void write_out(const int* __restrict__ winner,
                                                 float* __restrict__ out)
{
    int row = blockIdx.x;
    int win = winner[row];
    float4* o = (float4*)(out + (size_t)row*NV);
    int tid = threadIdx.x;
    #pragma unroll
    for (int i = 0; i < 10; i++) {
        int idx = tid + i*256;
        if (idx < 2500) {
            int vb = idx*4;
            float4 val = {0.f, 0.f, 0.f, 0.f};
            if (win >= vb && win < vb+4) ((float*)&val)[win - vb] = 1.0f;
            o[idx] = val;
        }
    }
}

extern "C" void kernel_launch(void* const* d_in, const int* in_sizes, int n_in,
                              void* d_out, int out_size, void* d_ws, size_t ws_size,
                              hipStream_t stream)
{
    const int*   ids   = (const int*)d_in[0];
    const int*   mask  = (const int*)d_in[1];
    const float* eEmb  = (const float*)d_in[2];
    const float* eWih  = (const float*)d_in[3];
    const float* eWhh  = (const float*)d_in[4];
    const float* eB    = (const float*)d_in[5];
    const float* dEmb  = (const float*)d_in[6];
    const float* dWih  = (const float*)d_in[7];
    const float* dWhh  = (const float*)d_in[8];
    const float* dB    = (const float*)d_in[9];
    const float* fcW   = (const float*)d_in[10];
    const float* fcb   = (const float*)d_in[11];
    const float* rinit = (const float*)d_in[12];
    const float* gum   = (const float*)d_in[13];
    float* out = (float*)d_out;

    float* wsf = (float*)d_ws;
    size_t off = 0;
    float* Xenc = wsf + off; off += (size_t)TT*BB*G4;      // [t][col][b]
    float* Xdec = wsf + off; off += (size_t)TD*BB*G4;
    unsigned int* h_pk = (unsigned int*)(wsf + off); off += 2*(size_t)BB*HID;
    float* hs   = wsf + off; off += (size_t)TD*BB*HID;
    float* fcWt = wsf + off; off += (size_t)NV*HID;
    float* Mr   = wsf + off; off += 4096;
    unsigned int* scal = (unsigned int*)(wsf + off); off += 8;
    int* flags  = (int*)(wsf + off); off += NB;
    int* exclk  = (int*)(wsf + off); off += 4096;
    int* winner = (int*)(wsf + off); off += 4096;

    hipMemsetAsync(scal,  0, 8*sizeof(int), stream);
    hipMemsetAsync(flags, 0, NB*sizeof(int), stream);

    dim3 gblk(16, 32);
    gemm_x<<<gblk, 256, 0, stream>>>(ids, eEmb, eWih, eB, Xenc, TT*BB);
    gemm_x<<<gblk, 256, 0, stream>>>(ids, dEmb, dWih, dB, Xdec, TD*BB);
    transpose_fc<<<dim3(313,16), dim3(32,8), 0, stream>>>(fcW, fcWt);
    wnorm<<<40, 256, 0, stream>>>(fcW, fcb, scal);
    routing<<<32, 128, 0, stream>>>(ids, mask, exclk, winner);

    lstm_persist<<<NB, 512, 0, stream>>>(Xenc, Xdec, eWhh, dWhh, h_pk, hs, flags);

    hnorm<<<TD*BB, 64, 0, stream>>>(hs, scal);
    rowmax<<<4096, 256, 0, stream>>>(mask, exclk, gum, Mr);
    cand_argmax<<<4096, 256, 0, stream>>>(mask, exclk, gum, rinit, hs, fcWt, fcb, Mr, scal, winner);
    write_out<<<4096, 256, 0, stream>>>(winner, out);
}

// Round 5
// 1151.990 us; speedup vs baseline: 5.7303x; 1.6088x over previous
//
#include <hip/hip_runtime.h>
#include <hip/hip_bf16.h>
#include <math.h>

#define BB 32
#define TT 128
#define TD 127
#define EMB 256
#define HID 512
#define G4 2048
#define NV 10000
#define NB 64
#define UPB 8      // units per block -> 32 gate cols

typedef __attribute__((ext_vector_type(8))) short short8v;
typedef __attribute__((ext_vector_type(4))) float f32x4;

__device__ __forceinline__ unsigned short bf16_rne(float x){
    unsigned int u = __float_as_uint(x);
    u += 0x7fffu + ((u >> 16) & 1u);
    return (unsigned short)(u >> 16);
}
__device__ __forceinline__ float bf16f(unsigned short h){
    return __uint_as_float(((unsigned int)h) << 16);
}

// ---------------- GEMM: X[t][col][b] = embed[tok] @ W + bias ----------------
__global__ __launch_bounds__(256) void gemm_x(const int* __restrict__ ids,
        const float* __restrict__ embed, const float* __restrict__ W,
        const float* __restrict__ bias, float* __restrict__ X, int M)
{
    __shared__ float As[16][128];
    __shared__ float Bs[16][128];
    __shared__ int toks[128];
    const int tid = threadIdx.x;
    const int m0 = blockIdx.y * 128, n0 = blockIdx.x * 128;
    if (tid < 128) {
        int mr = m0 + tid, tk = 0;
        if (mr < M) { int t = mr >> 5, b = mr & 31; tk = ids[b*TT + t]; }
        toks[tid] = tk;
    }
    __syncthreads();
    float acc[8][8] = {};
    const int ty = tid >> 4, tx = tid & 15;
    for (int kt = 0; kt < EMB; kt += 16) {
        #pragma unroll
        for (int i = 0; i < 2; i++) {
            int idx = tid*2 + i;
            int row = idx >> 2, k4 = (idx & 3)*4;
            float4 a = *(const float4*)&embed[(size_t)toks[row]*EMB + kt + k4];
            As[k4+0][row] = a.x; As[k4+1][row] = a.y; As[k4+2][row] = a.z; As[k4+3][row] = a.w;
        }
        #pragma unroll
        for (int i = 0; i < 2; i++) {
            int idx = tid*2 + i;
            int kr = idx >> 5, c4 = (idx & 31)*4;
            *(float4*)&Bs[kr][c4] = *(const float4*)&W[(size_t)(kt+kr)*G4 + n0 + c4];
        }
        __syncthreads();
        #pragma unroll
        for (int k = 0; k < 16; k++) {
            float a8[8], b8[8];
            #pragma unroll
            for (int i = 0; i < 8; i++) a8[i] = As[k][ty*8+i];
            #pragma unroll
            for (int j = 0; j < 8; j++) b8[j] = Bs[k][tx*8+j];
            #pragma unroll
            for (int i = 0; i < 8; i++) {
                #pragma unroll
                for (int j = 0; j < 8; j++)
                    acc[i][j] = fmaf(a8[i], b8[j], acc[i][j]);
            }
        }
        __syncthreads();
    }
    #pragma unroll
    for (int i = 0; i < 8; i++) {
        int mr = m0 + ty*8 + i;
        if (mr < M) {
            int tt = mr >> 5, bb2 = mr & 31;
            #pragma unroll
            for (int j = 0; j < 8; j++) {
                int nc = n0 + tx*8 + j;
                X[((size_t)tt*G4 + nc)*BB + bb2] = acc[i][j] + bias[nc];
            }
        }
    }
}

// ---------------- Persistent MFMA LSTM ----------------
// 64 blocks x 512 thr (8 waves). Block owns 8 units -> 32 gate cols (2 N-tiles).
// Wave w: K-slice [64w, 64w+64). W frags rebuilt per phase, live in VGPRs.
// Sync: all h traffic is sc1 relaxed-atomic (L2-bypassing). __syncthreads'
// vmcnt(0) drain puts them at the coherence point, so the flag store is
// RELAXED (no release -> no buffer_wbl2 on the critical path). hs-history
// store and X staging are issued AFTER the flag store (off critical path).
__global__ __launch_bounds__(512) void lstm_persist(
        const float* __restrict__ Xenc, const float* __restrict__ Xdec,
        const float* __restrict__ Whh_e, const float* __restrict__ Whh_d,
        unsigned int* __restrict__ h_pk,   // [2][512][32]
        float* __restrict__ hs,            // [127][32][512]
        int* __restrict__ flags)           // [64]
{
    __shared__ float smem[10272];          // partials [8][32][36] + xbuf [32][33]
    float* partials = smem;                // 9216 floats (also W-stage scratch)
    float* xbuf     = smem + 9216;         // 1056 floats

    const int tid = threadIdx.x;
    const int bid = blockIdx.x;
    const int u0  = bid*UPB;
    const int w   = tid >> 6;
    const int l   = tid & 63;
    const int rl  = l & 15;                // A-row / B-col / C-col in tile
    const int kg  = (l >> 4) * 8;          // frag k sub-base
    const int r4  = (l >> 4) * 4;          // C row base

    short8v wH_n0k0, wH_n0k1, wH_n1k0, wH_n1k1;
    short8v wL_n0k0, wL_n0k1, wL_n1k0, wL_n1k1;

    #define BW(WH, WL, KB, CO) do { _Pragma("unroll") \
        for (int j = 0; j < 8; ++j) { \
            float wv = partials[((KB)+j)*32 + (CO) + rl]; \
            unsigned short h2 = bf16_rne(wv); \
            WH[j] = (short)h2; \
            WL[j] = (short)bf16_rne(wv - bf16f(h2)); \
        } } while(0)

    #define STAGE_BUILD(SRC) do { \
        for (int c = 0; c < 4; ++c) { \
            int k0 = c*128; \
            __syncthreads(); \
            for (int i = tid; i < 4096; i += 512) { \
                int kl = i >> 5, n = i & 31; \
                partials[kl*32 + n] = SRC[(size_t)(k0+kl)*G4 + (size_t)((n>>3)*512 + u0 + (n&7))]; \
            } \
            __syncthreads(); \
            if ((w >> 1) == c) { \
                int kb0 = w*64 - k0 + kg; \
                BW(wH_n0k0, wL_n0k0, kb0,      0); \
                BW(wH_n0k1, wL_n0k1, kb0 + 32, 0); \
                BW(wH_n1k0, wL_n1k0, kb0,     16); \
                BW(wH_n1k1, wL_n1k1, kb0 + 32,16); \
            } \
        } \
        __syncthreads(); } while(0)

    STAGE_BUILD(Whh_e);

    {   // prologue: stage X tile for step 0
        for (int i = tid; i < 1024; i += 512) {
            int row = i & 31, n = i >> 5;
            xbuf[row*33 + n] = Xenc[(size_t)((n>>3)*512 + u0 + (n&7))*32 + row];
        }
        __syncthreads();
    }

    float c_reg = 0.f;
    const int gb = tid >> 3, gul = tid & 7;    // gate-thread mapping (tid<256)

    for (int gstep = 0; gstep < TT + TD; ++gstep) {
        const bool enc = gstep < TT;
        const int t = enc ? gstep : gstep - TT;

        f32x4 acc00 = {0,0,0,0}, acc01 = {0,0,0,0}, acc10 = {0,0,0,0}, acc11 = {0,0,0,0};
        if (gstep > 0) {
            const unsigned int* hp = h_pk + (size_t)(gstep & 1)*16384;
            short8v aH_m0k0, aH_m0k1, aH_m1k0, aH_m1k1;
            short8v aL_m0k0, aL_m0k1, aL_m1k0, aL_m1k1;
            #define LOAD_A(AH, AL, MT, KS) do { \
                unsigned int pv[8]; \
                int kbase = w*64 + (KS)*32 + kg; \
                int brow = (MT)*16 + rl; \
                _Pragma("unroll") \
                for (int j = 0; j < 8; ++j) \
                    pv[j] = __hip_atomic_load(&hp[(kbase+j)*32 + brow], \
                                __ATOMIC_RELAXED, __HIP_MEMORY_SCOPE_AGENT); \
                _Pragma("unroll") \
                for (int j = 0; j < 8; ++j) { \
                    AH[j] = (short)(pv[j] & 0xffffu); \
                    AL[j] = (short)(pv[j] >> 16); \
                } } while(0)
            LOAD_A(aH_m0k0, aL_m0k0, 0, 0); LOAD_A(aH_m0k1, aL_m0k1, 0, 1);
            LOAD_A(aH_m1k0, aL_m1k0, 1, 0); LOAD_A(aH_m1k1, aL_m1k1, 1, 1);
            #define MM6(ACC, AH0, AH1, AL0, AL1, WH0, WH1, WL0, WL1) do { \
                ACC = __builtin_amdgcn_mfma_f32_16x16x32_bf16(AH0, WH0, ACC, 0,0,0); \
                ACC = __builtin_amdgcn_mfma_f32_16x16x32_bf16(AH1, WH1, ACC, 0,0,0); \
                ACC = __builtin_amdgcn_mfma_f32_16x16x32_bf16(AL0, WH0, ACC, 0,0,0); \
                ACC = __builtin_amdgcn_mfma_f32_16x16x32_bf16(AL1, WH1, ACC, 0,0,0); \
                ACC = __builtin_amdgcn_mfma_f32_16x16x32_bf16(AH0, WL0, ACC, 0,0,0); \
                ACC = __builtin_amdgcn_mfma_f32_16x16x32_bf16(AH1, WL1, ACC, 0,0,0); \
            } while(0)
            MM6(acc00, aH_m0k0, aH_m0k1, aL_m0k0, aL_m0k1, wH_n0k0, wH_n0k1, wL_n0k0, wL_n0k1);
            MM6(acc01, aH_m0k0, aH_m0k1, aL_m0k0, aL_m0k1, wH_n1k0, wH_n1k1, wL_n1k0, wL_n1k1);
            MM6(acc10, aH_m1k0, aH_m1k1, aL_m1k0, aL_m1k1, wH_n0k0, wH_n0k1, wL_n0k0, wL_n0k1);
            MM6(acc11, aH_m1k0, aH_m1k1, aL_m1k0, aL_m1k1, wH_n1k0, wH_n1k1, wL_n1k0, wL_n1k1);
        }
        // C -> LDS partials [w][row32][col32+pad]
        #pragma unroll
        for (int j = 0; j < 4; ++j) {
            partials[(w*32 +      r4 + j)*36 +      rl] = acc00[j];
            partials[(w*32 +      r4 + j)*36 + 16 + rl] = acc01[j];
            partials[(w*32 + 16 + r4 + j)*36 +      rl] = acc10[j];
            partials[(w*32 + 16 + r4 + j)*36 + 16 + rl] = acc11[j];
        }
        __syncthreads();

        float hv = 0.f;
        if (tid < 256) {
            float pre[4];
            #pragma unroll
            for (int g = 0; g < 4; ++g) {
                float s = xbuf[gb*33 + g*8 + gul];
                #pragma unroll
                for (int ww = 0; ww < 8; ++ww)
                    s += partials[(ww*32 + gb)*36 + g*8 + gul];
                pre[g] = s;
            }
            float iv = 1.f/(1.f + expf(-pre[0]));
            float fv = 1.f/(1.f + expf(-pre[1]));
            float gv = tanhf(pre[2]);
            float ov = 1.f/(1.f + expf(-pre[3]));
            c_reg = fmaf(fv, c_reg, iv*gv);
            hv = ov * tanhf(c_reg);
            unsigned short hh = bf16_rne(hv);
            unsigned short hl = bf16_rne(hv - bf16f(hh));
            unsigned int pk = (unsigned int)hh | ((unsigned int)hl << 16);
            __hip_atomic_store(&h_pk[(size_t)((gstep+1) & 1)*16384 + (u0+gul)*32 + gb],
                               pk, __ATOMIC_RELAXED, __HIP_MEMORY_SCOPE_AGENT);
        }
        __syncthreads();                   // vmcnt(0): all h_pk sc1 stores at L3
        // flag FIRST (relaxed: prior sc1 stores already at coherence point)
        if (gstep < TT + TD - 1 && tid == 0)
            __hip_atomic_store(&flags[bid], gstep + 1,
                               __ATOMIC_RELAXED, __HIP_MEMORY_SCOPE_AGENT);
        // off-critical-path work
        if (!enc && tid < 256)
            hs[((size_t)t*BB + gb)*HID + u0 + gul] = hv;
        if (gstep == TT + TD - 1) break;

        if (gstep == TT - 1) STAGE_BUILD(Whh_d);   // phase switch (uniform)

        {   // stage X for next step (overlaps the poll wait)
            int tn = gstep + 1 < TT ? gstep + 1 : gstep + 1 - TT;
            const float* Xt = (gstep + 1 < TT ? Xenc : Xdec) + (size_t)tn*G4*BB;
            for (int i = tid; i < 1024; i += 512) {
                int row = i & 31, n = i >> 5;
                xbuf[row*33 + n] = Xt[(size_t)((n>>3)*512 + u0 + (n&7))*32 + row];
            }
        }
        if (tid < NB) {
            while (__hip_atomic_load(&flags[tid], __ATOMIC_RELAXED,
                                     __HIP_MEMORY_SCOPE_AGENT) <= gstep) {}
        }
        __syncthreads();
        asm volatile("" ::: "memory");
    }
}

// ---------------- transpose fc_W (512 x 10000) -> (10000 x 512) ----------------
__global__ void transpose_fc(const float* __restrict__ W, float* __restrict__ Wt)
{
    __shared__ float tile[32][33];
    int v0 = blockIdx.x*32, k0 = blockIdx.y*32;
    int tx = threadIdx.x, ty = threadIdx.y;  // (32,8)
    #pragma unroll
    for (int r = 0; r < 32; r += 8) {
        int k = k0 + ty + r, v = v0 + tx;
        tile[ty+r][tx] = (v < NV) ? W[(size_t)k*NV + v] : 0.f;
    }
    __syncthreads();
    #pragma unroll
    for (int r = 0; r < 32; r += 8) {
        int v = v0 + ty + r, k = k0 + tx;
        if (v < NV) Wt[(size_t)v*HID + k] = tile[tx][ty+r];
    }
}

// ---------------- norms for rigorous logit bound ----------------
__global__ void wnorm(const float* __restrict__ W, const float* __restrict__ bvec,
                      unsigned int* __restrict__ scal)
{
    int v = blockIdx.x*256 + threadIdx.x;
    if (v < NV) {
        float s = 0.f;
        for (int k = 0; k < HID; k++) { float w = W[(size_t)k*NV + v]; s = fmaf(w, w, s); }
        atomicMax(&scal[0], __float_as_uint(s));
        atomicMax(&scal[1], __float_as_uint(fabsf(bvec[v])));
    }
}

__global__ void hnorm(const float* __restrict__ hs, unsigned int* __restrict__ scal)
{
    int r = blockIdx.x, lane = threadIdx.x;  // 64 threads
    float s = 0.f;
    for (int k = lane; k < HID; k += 64) { float x = hs[(size_t)r*HID + k]; s = fmaf(x, x, s); }
    for (int o = 32; o; o >>= 1) s += __shfl_down(s, o);
    if (lane == 0) atomicMax(&scal[2], __float_as_uint(s));
}

// ---------------- routing ----------------
__global__ void routing(const int* __restrict__ ids, const int* __restrict__ mask,
                        int* __restrict__ exclk, int* __restrict__ winner)
{
    int b = blockIdx.x;
    __shared__ int pre[TT];
    int t = threadIdx.x;
    if (t == 0) { int s = 0; for (int i = 0; i < TT; i++) { pre[i] = s; s += mask[b*TT+i]; } }
    __syncthreads();
    exclk[b*TT + t] = pre[t];
    if (mask[b*TT + t] == 0) winner[b*TT + t] = ids[b*TT + t];
}

// ---------------- per-row gumbel max ----------------
__global__ __launch_bounds__(256) void rowmax(const int* __restrict__ mask,
        const int* __restrict__ exclk, const float* __restrict__ gum, float* __restrict__ Mr)
{
    int row = blockIdx.x, b = row >> 7, t = row & 127;
    if (t == 0 || mask[row] == 0) return;
    int k = exclk[row];
    const float* g = gum + ((size_t)k*BB + b)*NV;
    float m = -1e30f;
    for (int v = threadIdx.x; v < NV; v += 256) m = fmaxf(m, g[v]);
    __shared__ float red[256];
    red[threadIdx.x] = m; __syncthreads();
    for (int s = 128; s; s >>= 1) {
        if (threadIdx.x < s) red[threadIdx.x] = fmaxf(red[threadIdx.x], red[threadIdx.x+s]);
        __syncthreads();
    }
    if (threadIdx.x == 0) Mr[row] = red[0];
}

// ---------------- candidate scan + exact fp32 logits + argmax ----------------
__global__ __launch_bounds__(256) void cand_argmax(const int* __restrict__ mask,
        const int* __restrict__ exclk, const float* __restrict__ gum,
        const float* __restrict__ rinit, const float* __restrict__ hs,
        const float* __restrict__ Wt, const float* __restrict__ fcb,
        const float* __restrict__ Mr, const unsigned int* __restrict__ scal,
        int* __restrict__ winner)
{
    int row = blockIdx.x, b = row >> 7, t = row & 127;
    if (mask[row] == 0) return;
    int tid = threadIdx.x;
    __shared__ float red[256];
    __shared__ int idxr[256];
    __shared__ int list[256];
    __shared__ int wcnt[4];

    if (t == 0) {
        const float* g  = gum   + (size_t)b*NV;
        const float* r0 = rinit + (size_t)b*NV;
        float bs = -1e30f; int bv = 0x7fffffff;
        for (int v = tid; v < NV; v += 256) {
            float sc = r0[v] + g[v];
            if (sc > bs) { bs = sc; bv = v; }
        }
        red[tid] = bs; idxr[tid] = bv; __syncthreads();
        for (int s = 128; s; s >>= 1) {
            if (tid < s) {
                if (red[tid+s] > red[tid] || (red[tid+s] == red[tid] && idxr[tid+s] < idxr[tid])) {
                    red[tid] = red[tid+s]; idxr[tid] = idxr[tid+s];
                }
            }
            __syncthreads();
        }
        if (tid == 0) winner[row] = idxr[0];
        return;
    }

    int k = exclk[row];
    const float* g    = gum + ((size_t)k*BB + b)*NV;
    const float* hrow = hs + ((size_t)(t-1)*BB + b)*HID;
    float bound = sqrtf(__uint_as_float(scal[0])) * sqrtf(__uint_as_float(scal[2]))
                + __uint_as_float(scal[1]);
    float thr = Mr[row] - 2.0f*bound*1.05f - 1e-6f;

    float curS = -1e30f; int curV = 0x7fffffff;
    int wv = tid >> 6, lane = tid & 63;
    for (int v0 = 0; v0 < NV; v0 += 256) {
        int v = v0 + tid;
        bool ok = (v < NV) && (g[v] >= thr);
        unsigned long long mb = __ballot(ok);
        if (lane == 0) wcnt[wv] = __popcll(mb);
        __syncthreads();
        int off = 0;
        #pragma unroll
        for (int w = 0; w < 4; w++) if (w < wv) off += wcnt[w];
        int tot = wcnt[0] + wcnt[1] + wcnt[2] + wcnt[3];
        if (ok) {
            int pos = off + __popcll(mb & ((1ull << lane) - 1ull));
            list[pos] = v;
        }
        __syncthreads();
        for (int ci = 0; ci < tot; ci++) {
            int vc = list[ci];
            float p = 0.f;
            for (int k2 = tid; k2 < HID; k2 += 256)
                p = fmaf(hrow[k2], Wt[(size_t)vc*HID + k2], p);
            red[tid] = p; __syncthreads();
            for (int s = 128; s; s >>= 1) {
                if (tid < s) red[tid] += red[tid+s];
                __syncthreads();
            }
            if (tid == 0) {
                float sc = (red[0] + fcb[vc]) + g[vc];
                if (sc > curS || (sc == curS && vc < curV)) { curS = sc; curV = vc; }
            }
            __syncthreads();
        }
    }
    if (tid == 0) winner[row] = curV;
}

// ---------------- write one-hot output ----------------
__global__ __launch_bounds__(256) void write_out(const int* __restrict__ winner,
                                                 float* __restrict__ out)
{
    int row = blockIdx.x;
    int win = winner[row];
    float4* o = (float4*)(out + (size_t)row*NV);
    int tid = threadIdx.x;
    #pragma unroll
    for (int i = 0; i < 10; i++) {
        int idx = tid + i*256;
        if (idx < 2500) {
            int vb = idx*4;
            float4 val = {0.f, 0.f, 0.f, 0.f};
            if (win >= vb && win < vb+4) ((float*)&val)[win - vb] = 1.0f;
            o[idx] = val;
        }
    }
}

extern "C" void kernel_launch(void* const* d_in, const int* in_sizes, int n_in,
                              void* d_out, int out_size, void* d_ws, size_t ws_size,
                              hipStream_t stream)
{
    const int*   ids   = (const int*)d_in[0];
    const int*   mask  = (const int*)d_in[1];
    const float* eEmb  = (const float*)d_in[2];
    const float* eWih  = (const float*)d_in[3];
    const float* eWhh  = (const float*)d_in[4];
    const float* eB    = (const float*)d_in[5];
    const float* dEmb  = (const float*)d_in[6];
    const float* dWih  = (const float*)d_in[7];
    const float* dWhh  = (const float*)d_in[8];
    const float* dB    = (const float*)d_in[9];
    const float* fcW   = (const float*)d_in[10];
    const float* fcb   = (const float*)d_in[11];
    const float* rinit = (const float*)d_in[12];
    const float* gum   = (const float*)d_in[13];
    float* out = (float*)d_out;

    float* wsf = (float*)d_ws;
    size_t off = 0;
    float* Xenc = wsf + off; off += (size_t)TT*BB*G4;      // [t][col][b]
    float* Xdec = wsf + off; off += (size_t)TD*BB*G4;
    unsigned int* h_pk = (unsigned int*)(wsf + off); off += 2*(size_t)BB*HID;
    float* hs   = wsf + off; off += (size_t)TD*BB*HID;
    float* fcWt = wsf + off; off += (size_t)NV*HID;
    float* Mr   = wsf + off; off += 4096;
    unsigned int* scal = (unsigned int*)(wsf + off); off += 8;
    int* flags  = (int*)(wsf + off); off += NB;
    int* exclk  = (int*)(wsf + off); off += 4096;
    int* winner = (int*)(wsf + off); off += 4096;

    hipMemsetAsync(scal,  0, 8*sizeof(int), stream);
    hipMemsetAsync(flags, 0, NB*sizeof(int), stream);

    dim3 gblk(16, 32);
    gemm_x<<<gblk, 256, 0, stream>>>(ids, eEmb, eWih, eB, Xenc, TT*BB);
    gemm_x<<<gblk, 256, 0, stream>>>(ids, dEmb, dWih, dB, Xdec, TD*BB);
    transpose_fc<<<dim3(313,16), dim3(32,8), 0, stream>>>(fcW, fcWt);
    wnorm<<<40, 256, 0, stream>>>(fcW, fcb, scal);
    routing<<<32, 128, 0, stream>>>(ids, mask, exclk, winner);

    lstm_persist<<<NB, 512, 0, stream>>>(Xenc, Xdec, eWhh, dWhh, h_pk, hs, flags);

    hnorm<<<TD*BB, 64, 0, stream>>>(hs, scal);
    rowmax<<<4096, 256, 0, stream>>>(mask, exclk, gum, Mr);
    cand_argmax<<<4096, 256, 0, stream>>>(mask, exclk, gum, rinit, hs, fcWt, fcb, Mr, scal, winner);
    write_out<<<4096, 256, 0, stream>>>(winner, out);
}